// Round 1
// baseline (568.609 us; speedup 1.0000x reference)
//
#include <hip/hip_runtime.h>
#include <hip/hip_bf16.h>

// Problem constants: T=128, N=256, E=128, M=8 heads, D=16, tokens=32768.
#define F_EL 4194304ull  // T*N*E

__device__ __forceinline__ float4 ld4(const float* p) { return *(const float4*)p; }

// C[row][col] = act( sum_k A[row][k] * W[col][k] + bias[col] (+ res[row][col]) )
// Tile: 128 rows x 128 cols, BK=32, 256 threads, 8x8 per thread.
// QKV mode: blockIdx.y in {0,1,2} selects (W,bias,out); PERM writes [T][M][N][D].
template<bool RELU, bool PERM, bool RES, bool QKV>
__global__ __launch_bounds__(256)
void gemm_k(const float* __restrict__ A,
            const float* __restrict__ Wa, const float* __restrict__ Ba,
            const float* __restrict__ Wb, const float* __restrict__ Bb,
            const float* __restrict__ Wc, const float* __restrict__ Bc,
            float* __restrict__ Oa, float* __restrict__ Ob, float* __restrict__ Oc,
            const float* __restrict__ res, int K, int Nout)
{
  const float* W = Wa; const float* bias = Ba; float* out = Oa;
  int col0 = 0;
  if constexpr (QKV) {
    if (blockIdx.y == 1) { W = Wb; bias = Bb; out = Ob; }
    if (blockIdx.y == 2) { W = Wc; bias = Bc; out = Oc; }
  } else {
    col0 = blockIdx.y * 128;
  }

  __shared__ float At[32 * 128];  // At[k][row]  (transposed for contiguous reads)
  __shared__ float Wt[32 * 128];  // Wt[k][col]

  const int t  = threadIdx.x;
  const int tx = t & 15;
  const int ty = t >> 4;
  const int row0 = blockIdx.x * 128;

  float acc[8][8];
#pragma unroll
  for (int i = 0; i < 8; ++i)
#pragma unroll
    for (int j = 0; j < 8; ++j) acc[i][j] = 0.f;

  // staging: thread loads row lr, 16 consecutive k (2-way LDS write aliasing = free)
  const int lr = t >> 1;
  const int lc = (t & 1) * 16;
  const float* Ap = A + (size_t)(row0 + lr) * K + lc;
  const float* Wp = W + (size_t)(col0 + lr) * K + lc;

  for (int k0 = 0; k0 < K; k0 += 32) {
    float4 ga[4], gw[4];
#pragma unroll
    for (int i = 0; i < 4; ++i) ga[i] = ld4(Ap + k0 + i * 4);
#pragma unroll
    for (int i = 0; i < 4; ++i) gw[i] = ld4(Wp + k0 + i * 4);
    __syncthreads();
#pragma unroll
    for (int i = 0; i < 4; ++i) {
      const int c = lc + i * 4;
      At[(c + 0) * 128 + lr] = ga[i].x;
      At[(c + 1) * 128 + lr] = ga[i].y;
      At[(c + 2) * 128 + lr] = ga[i].z;
      At[(c + 3) * 128 + lr] = ga[i].w;
      Wt[(c + 0) * 128 + lr] = gw[i].x;
      Wt[(c + 1) * 128 + lr] = gw[i].y;
      Wt[(c + 2) * 128 + lr] = gw[i].z;
      Wt[(c + 3) * 128 + lr] = gw[i].w;
    }
    __syncthreads();
#pragma unroll
    for (int k = 0; k < 32; ++k) {
      const float4 a0 = ld4(&At[k * 128 + ty * 4]);
      const float4 a1 = ld4(&At[k * 128 + 64 + ty * 4]);
      const float4 w0 = ld4(&Wt[k * 128 + tx * 4]);
      const float4 w1 = ld4(&Wt[k * 128 + 64 + tx * 4]);
      const float ar[8] = {a0.x,a0.y,a0.z,a0.w,a1.x,a1.y,a1.z,a1.w};
      const float wr[8] = {w0.x,w0.y,w0.z,w0.w,w1.x,w1.y,w1.z,w1.w};
#pragma unroll
      for (int i = 0; i < 8; ++i)
#pragma unroll
        for (int j = 0; j < 8; ++j) acc[i][j] = fmaf(ar[i], wr[j], acc[i][j]);
    }
  }

  const float4 bva = ld4(bias + col0 + tx * 4);
  const float4 bvb = ld4(bias + col0 + 64 + tx * 4);
  const float br[8] = {bva.x,bva.y,bva.z,bva.w,bvb.x,bvb.y,bvb.z,bvb.w};

#pragma unroll
  for (int i = 0; i < 8; ++i) {
    const int row = row0 + ((i < 4) ? (ty * 4 + i) : (64 + ty * 4 + (i - 4)));
    float o[8];
#pragma unroll
    for (int j = 0; j < 8; ++j) o[j] = acc[i][j] + br[j];
    if constexpr (RES) {  // residual stride is always 128 (E) where used
      const float4 r0 = ld4(res + (size_t)row * 128 + col0 + tx * 4);
      const float4 r1 = ld4(res + (size_t)row * 128 + col0 + 64 + tx * 4);
      o[0]+=r0.x; o[1]+=r0.y; o[2]+=r0.z; o[3]+=r0.w;
      o[4]+=r1.x; o[5]+=r1.y; o[6]+=r1.z; o[7]+=r1.w;
    }
    if constexpr (RELU) {
#pragma unroll
      for (int j = 0; j < 8; ++j) o[j] = fmaxf(o[j], 0.f);
    }
    const float4 va = {o[0],o[1],o[2],o[3]};
    const float4 vb = {o[4],o[5],o[6],o[7]};
    if constexpr (PERM) {
      // write q/k/v as [T][M][N][D]: ((tt*8+m)*256+n)*16+d
      const int tt = row >> 8, n = row & 255;
      const int ca = tx * 4, cb = 64 + tx * 4;
      float* pa = out + ((((size_t)tt * 8) + (ca >> 4)) * 256 + n) * 16 + (ca & 15);
      float* pb = out + ((((size_t)tt * 8) + (cb >> 4)) * 256 + n) * 16 + (cb & 15);
      *(float4*)pa = va;
      *(float4*)pb = vb;
    } else {
      *(float4*)(out + (size_t)row * Nout + col0 + tx * 4) = va;
      *(float4*)(out + (size_t)row * Nout + col0 + 64 + tx * 4) = vb;
    }
  }
}

// One block per (t, head m). 256 threads = 1 query each. K,V panels in LDS.
// Online-softmax single pass. q/k/v layout [T][M][N][D]; out layout [T][N][E].
__global__ __launch_bounds__(256)
void attn_k(const float* __restrict__ q, const float* __restrict__ k,
            const float* __restrict__ v, float* __restrict__ out)
{
  __shared__ float Kl[4096];
  __shared__ float Vl[4096];
  const int tm = blockIdx.x;          // t*8 + m
  const int tt = tm >> 3, m = tm & 7;
  const int n = threadIdx.x;

  const float4* kb = (const float4*)(k + (size_t)tm * 4096);
  const float4* vb = (const float4*)(v + (size_t)tm * 4096);
  float4* Kl4 = (float4*)Kl;
  float4* Vl4 = (float4*)Vl;
#pragma unroll
  for (int i = 0; i < 4; ++i) {
    Kl4[n * 4 + i] = kb[n * 4 + i];
    Vl4[n * 4 + i] = vb[n * 4 + i];
  }
  const float* qp = q + (size_t)tm * 4096 + n * 16;
  const float4 q0 = ld4(qp), q1 = ld4(qp + 4), q2 = ld4(qp + 8), q3 = ld4(qp + 12);
  __syncthreads();

  float mmax = -3.0e38f, ssum = 0.f;
  float acc[16];
#pragma unroll
  for (int d = 0; d < 16; ++d) acc[d] = 0.f;

#pragma unroll 4
  for (int j = 0; j < 256; ++j) {
    const float4 k0 = Kl4[j*4+0], k1 = Kl4[j*4+1], k2 = Kl4[j*4+2], k3 = Kl4[j*4+3];
    float s = q0.x*k0.x + q0.y*k0.y + q0.z*k0.z + q0.w*k0.w;
    s += q1.x*k1.x + q1.y*k1.y + q1.z*k1.z + q1.w*k1.w;
    s += q2.x*k2.x + q2.y*k2.y + q2.z*k2.z + q2.w*k2.w;
    s += q3.x*k3.x + q3.y*k3.y + q3.z*k3.z + q3.w*k3.w;
    s *= 0.25f;  // 1/sqrt(dk), dk = E/M = 16
    const float nm = fmaxf(mmax, s);
    const float cf = __expf(mmax - nm);
    const float p  = __expf(s - nm);
    ssum = ssum * cf + p;
    mmax = nm;
    const float4 v0 = Vl4[j*4+0], v1 = Vl4[j*4+1], v2 = Vl4[j*4+2], v3 = Vl4[j*4+3];
    acc[ 0] = acc[ 0]*cf + p*v0.x;  acc[ 1] = acc[ 1]*cf + p*v0.y;
    acc[ 2] = acc[ 2]*cf + p*v0.z;  acc[ 3] = acc[ 3]*cf + p*v0.w;
    acc[ 4] = acc[ 4]*cf + p*v1.x;  acc[ 5] = acc[ 5]*cf + p*v1.y;
    acc[ 6] = acc[ 6]*cf + p*v1.z;  acc[ 7] = acc[ 7]*cf + p*v1.w;
    acc[ 8] = acc[ 8]*cf + p*v2.x;  acc[ 9] = acc[ 9]*cf + p*v2.y;
    acc[10] = acc[10]*cf + p*v2.z;  acc[11] = acc[11]*cf + p*v2.w;
    acc[12] = acc[12]*cf + p*v3.x;  acc[13] = acc[13]*cf + p*v3.y;
    acc[14] = acc[14]*cf + p*v3.z;  acc[15] = acc[15]*cf + p*v3.w;
  }
  const float inv = 1.f / ssum;
  float* op = out + (size_t)(tt * 256 + n) * 128 + m * 16;
  float4 o0 = {acc[0]*inv,  acc[1]*inv,  acc[2]*inv,  acc[3]*inv};
  float4 o1 = {acc[4]*inv,  acc[5]*inv,  acc[6]*inv,  acc[7]*inv};
  float4 o2 = {acc[8]*inv,  acc[9]*inv,  acc[10]*inv, acc[11]*inv};
  float4 o3 = {acc[12]*inv, acc[13]*inv, acc[14]*inv, acc[15]*inv};
  *(float4*)(op + 0)  = o0;
  *(float4*)(op + 4)  = o1;
  *(float4*)(op + 8)  = o2;
  *(float4*)(op + 12) = o3;
}

// BatchNorm over 32768 samples per channel (biased var), 2-stage deterministic.
__global__ __launch_bounds__(256)
void stats_partial(const float* __restrict__ x, float* __restrict__ part)
{
  const int b = blockIdx.x, t = threadIdx.x;
  const int c = t & 127, g = t >> 7;
  const float* xb = x + (size_t)b * 256 * 128;
  float s = 0.f, s2 = 0.f;
  for (int r = g; r < 256; r += 2) {
    const float vv = xb[(size_t)r * 128 + c];
    s += vv; s2 += vv * vv;
  }
  __shared__ float ls[256], ls2[256];
  ls[t] = s; ls2[t] = s2;
  __syncthreads();
  if (t < 128) {
    part[b * 128 + t]          = ls[t] + ls[t + 128];
    part[16384 + b * 128 + t]  = ls2[t] + ls2[t + 128];
  }
}

__global__ void stats_final(const float* __restrict__ part,
                            const float* __restrict__ gam, const float* __restrict__ bet,
                            float* __restrict__ AB)
{
  const int c = threadIdx.x;  // 128 threads
  float s = 0.f, s2 = 0.f;
  for (int b = 0; b < 128; ++b) { s += part[b*128 + c]; s2 += part[16384 + b*128 + c]; }
  const float invn = 1.f / 32768.f;
  const float mean = s * invn;
  const float var  = s2 * invn - mean * mean;
  const float rstd = rsqrtf(var + 1e-5f);
  const float Ac = gam[c] * rstd;
  AB[c] = Ac;
  AB[128 + c] = bet[c] - mean * Ac;
}

__global__ __launch_bounds__(256)
void bn_apply(float* __restrict__ x, const float* __restrict__ AB)
{
  __shared__ float sA[128], sB[128];
  const int t = threadIdx.x;
  if (t < 128) sA[t] = AB[t];
  else         sB[t - 128] = AB[t];
  __syncthreads();
  const size_t i = (size_t)blockIdx.x * 256 + t;
  float4 vv = ((float4*)x)[i];
  const int c = (int)((i * 4) & 127);
  vv.x = vv.x * sA[c + 0] + sB[c + 0];
  vv.y = vv.y * sA[c + 1] + sB[c + 1];
  vv.z = vv.z * sA[c + 2] + sB[c + 2];
  vv.w = vv.w * sA[c + 3] + sB[c + 3];
  ((float4*)x)[i] = vv;
}

extern "C" void kernel_launch(void* const* d_in, const int* in_sizes, int n_in,
                              void* d_out, int out_size, void* d_ws, size_t ws_size,
                              hipStream_t stream)
{
  (void)in_sizes; (void)n_in; (void)out_size; (void)ws_size;
  const float* node = (const float*)d_in[0];
  const float* Wq  = (const float*)d_in[1];
  const float* bq  = (const float*)d_in[2];
  const float* Wk  = (const float*)d_in[3];
  const float* bk  = (const float*)d_in[4];
  const float* Wv  = (const float*)d_in[5];
  const float* bv  = (const float*)d_in[6];
  const float* Ww  = (const float*)d_in[7];
  const float* bw  = (const float*)d_in[8];
  const float* Wf1 = (const float*)d_in[9];
  const float* bf1 = (const float*)d_in[10];
  const float* Wf2 = (const float*)d_in[11];
  const float* bf2 = (const float*)d_in[12];
  const float* g1  = (const float*)d_in[13];
  const float* be1 = (const float*)d_in[14];
  const float* g2  = (const float*)d_in[15];
  const float* be2 = (const float*)d_in[16];
  float* out = (float*)d_out;
  float* ws  = (float*)d_ws;

  // workspace layout (floats), peak ~48.3 MB:
  //  [0,1F): q  -> later x/xn        [1F,3F): k,v -> later FFN hidden (half tokens)
  //  [3F,4F): attn_out -> later stats region
  float* qb = ws + 0 * F_EL;
  float* kb = ws + 1 * F_EL;
  float* vb = ws + 2 * F_EL;
  float* ab = ws + 3 * F_EL;
  float* xb = ws + 0 * F_EL;
  float* hb = ws + 1 * F_EL;
  float* st = ws + 3 * F_EL;
  float* AB1 = st;
  float* AB2 = st + 256;
  float* part = st + 512;

  dim3 blk(256);

  // 1. Q,K,V projections (one launch, grid.y selects matrix), permuted layout
  gemm_k<false,true,false,true><<<dim3(256,3), blk, 0, stream>>>(
      node, Wq,bq, Wk,bk, Wv,bv, qb,kb,vb, nullptr, 128, 128);
  // 2. attention per (t, m)
  attn_k<<<dim3(1024), blk, 0, stream>>>(qb, kb, vb, ab);
  // 3. out-proj + node residual -> x
  gemm_k<false,false,true,false><<<dim3(256,1), blk, 0, stream>>>(
      ab, Ww,bw, Ww,bw, Ww,bw, xb,xb,xb, node, 128, 128);
  // 4. BN1 stats + apply in place (x -> xn)
  stats_partial<<<dim3(128), blk, 0, stream>>>(xb, part);
  stats_final<<<dim3(1), dim3(128), 0, stream>>>(part, g1, be1, AB1);
  bn_apply<<<dim3(4096), blk, 0, stream>>>(xb, AB1);
  // 5. FFN in two token halves (hidden reuses k/v region)
  for (int half = 0; half < 2; ++half) {
    const size_t ro = (size_t)half * 16384;
    gemm_k<true,false,false,false><<<dim3(128,4), blk, 0, stream>>>(
        xb + ro * 128, Wf1,bf1, Wf1,bf1, Wf1,bf1, hb,hb,hb, nullptr, 128, 512);
    gemm_k<false,false,true,false><<<dim3(128,1), blk, 0, stream>>>(
        hb, Wf2,bf2, Wf2,bf2, Wf2,bf2, out + ro * 128, out + ro * 128, out + ro * 128,
        xb + ro * 128, 512, 128);
  }
  // 6. BN2 stats + apply in place on d_out
  stats_partial<<<dim3(128), blk, 0, stream>>>(out, part);
  stats_final<<<dim3(1), dim3(128), 0, stream>>>(part, g2, be2, AB2);
  bn_apply<<<dim3(4096), blk, 0, stream>>>(out, AB2);
}

// Round 2
// 362.260 us; speedup vs baseline: 1.5696x; 1.5696x over previous
//
#include <hip/hip_runtime.h>
#include <stdint.h>

typedef unsigned int  uint32;
typedef unsigned short u16;
typedef __attribute__((ext_vector_type(8))) short short8;
typedef __attribute__((ext_vector_type(4))) float f32x4;

// ---------- bf16 helpers ----------
__device__ __forceinline__ float bits2f(uint32 u){ union{uint32 u; float f;} c; c.u=u; return c.f; }
__device__ __forceinline__ uint32 f2bits(float f){ union{uint32 u; float f;} c; c.f=f; return c.u; }
__device__ __forceinline__ u16 f2b(float f){ uint32 u=f2bits(f); return (u16)((u + 0x7FFFu + ((u>>16)&1u))>>16); }
__device__ __forceinline__ float b2f(u16 h){ return bits2f(((uint32)h)<<16); }
#define BLO(u) bits2f((u)<<16)
#define BHI(u) bits2f((u)&0xFFFF0000u)

// ---------- fp32 -> bf16 conversion of node + all weights (one launch) ----------
// float4 counts: node 1048576 | Wq/Wk/Wv/Ww 4096 each | Wf1/Wf2 16384 each = 1097728
__global__ __launch_bounds__(256)
void cvt_k(const float4* __restrict__ node,
           const float4* __restrict__ wq, const float4* __restrict__ wk,
           const float4* __restrict__ wv, const float4* __restrict__ ww,
           const float4* __restrict__ wf1, const float4* __restrict__ wf2,
           u16* __restrict__ nb, u16* __restrict__ wb)
{
  int i = blockIdx.x * 256 + threadIdx.x;
  const float4* src; u16* dst;
  if (i < 1048576) { src = node + i; dst = nb + (size_t)i*4; }
  else {
    int j = i - 1048576;
    if      (j <  4096) { src = wq  + j;          dst = wb +      0 + (size_t)j*4; }
    else if (j <  8192) { src = wk  + (j-4096);   dst = wb +  16384 + (size_t)(j-4096)*4; }
    else if (j < 12288) { src = wv  + (j-8192);   dst = wb +  32768 + (size_t)(j-8192)*4; }
    else if (j < 16384) { src = ww  + (j-12288);  dst = wb +  49152 + (size_t)(j-12288)*4; }
    else if (j < 32768) { src = wf1 + (j-16384);  dst = wb +  65536 + (size_t)(j-16384)*4; }
    else                { src = wf2 + (j-32768);  dst = wb + 131072 + (size_t)(j-32768)*4; }
  }
  float4 v = *src;
  uint2 o;
  o.x = (uint32)f2b(v.x) | ((uint32)f2b(v.y) << 16);
  o.y = (uint32)f2b(v.z) | ((uint32)f2b(v.w) << 16);
  *(uint2*)dst = o;
}

// ---------- bf16 MFMA GEMM: C[row][col] = act(sum_k A[row][k]*W[col][k] + bias[col] (+res)) ----------
// 128x128 tile, BK=64, 4 waves (2x2), each wave 4x4 tiles of 16x16x32 mfma.
// OUT: 0 = bf16 [row][Nout]; 1 = f32 [row][Nout]; 2 = bf16 QKV-perm [T][M][N][16]
// RES: 0 none; 1 f32 stride 128; 2 bf16 stride 128
template<int OUT, int RES, bool RELU>
__global__ __launch_bounds__(256)
void gemm_k(const u16* __restrict__ A, const u16* __restrict__ W,
            const float* __restrict__ bias, const void* __restrict__ res,
            void* __restrict__ out, int K, int Nout)
{
  __shared__ u16 As[128*72];   // rows x (64 + 8 pad) bf16
  __shared__ u16 Ws[128*72];
  const int t = threadIdx.x;
  const int row0 = blockIdx.x * 128;
  const int col0 = blockIdx.y * 128;
  const int L = t & 63, w = t >> 6;
  const int wrow = (w >> 1) * 64, wcol = (w & 1) * 64;
  const int lm = L & 15, lg = L >> 4;       // frag row/col-in-tile, k-group

  f32x4 acc[4][4];
#pragma unroll
  for (int i = 0; i < 4; ++i)
#pragma unroll
    for (int j = 0; j < 4; ++j) acc[i][j] = (f32x4){0.f,0.f,0.f,0.f};

  const int srow = t >> 1, skc = (t & 1) * 32;   // staging: row, k-chunk
  const u16* Ap = A + (size_t)(row0 + srow) * K + skc;
  const u16* Wp = W + (size_t)(col0 + srow) * K + skc;
  u16* Asp = As + srow * 72 + skc;
  u16* Wsp = Ws + srow * 72 + skc;

  for (int k0 = 0; k0 < K; k0 += 64) {
    short8 ga[4], gw[4];
#pragma unroll
    for (int i = 0; i < 4; ++i) ga[i] = *(const short8*)(Ap + k0 + i * 8);
#pragma unroll
    for (int i = 0; i < 4; ++i) gw[i] = *(const short8*)(Wp + k0 + i * 8);
    __syncthreads();   // previous tile fully consumed
#pragma unroll
    for (int i = 0; i < 4; ++i) *(short8*)(Asp + i * 8) = ga[i];
#pragma unroll
    for (int i = 0; i < 4; ++i) *(short8*)(Wsp + i * 8) = gw[i];
    __syncthreads();
#pragma unroll
    for (int ks = 0; ks < 64; ks += 32) {
      short8 af[4], wf[4];
#pragma unroll
      for (int i = 0; i < 4; ++i)
        af[i] = *(const short8*)(As + (wrow + i * 16 + lm) * 72 + ks + lg * 8);
#pragma unroll
      for (int j = 0; j < 4; ++j)
        wf[j] = *(const short8*)(Ws + (wcol + j * 16 + lm) * 72 + ks + lg * 8);
#pragma unroll
      for (int i = 0; i < 4; ++i)
#pragma unroll
        for (int j = 0; j < 4; ++j)
          acc[i][j] = __builtin_amdgcn_mfma_f32_16x16x32_bf16(af[i], wf[j], acc[i][j], 0, 0, 0);
    }
  }

  // epilogue: lane holds C[row=lg*4+r][col=lm] of each 16x16 tile
  float bj[4];
#pragma unroll
  for (int j = 0; j < 4; ++j) bj[j] = bias[col0 + wcol + j * 16 + lm];
#pragma unroll
  for (int i = 0; i < 4; ++i) {
    const int rowb = row0 + wrow + i * 16 + lg * 4;
#pragma unroll
    for (int j = 0; j < 4; ++j) {
      const int col = col0 + wcol + j * 16 + lm;
#pragma unroll
      for (int r = 0; r < 4; ++r) {
        const int row = rowb + r;
        float v = acc[i][j][r] + bj[j];
        if constexpr (RES == 1) v += ((const float*)res)[(size_t)row * 128 + col];
        if constexpr (RES == 2) v += b2f(((const u16*)res)[(size_t)row * 128 + col]);
        if constexpr (RELU) v = fmaxf(v, 0.f);
        if constexpr (OUT == 1) {
          ((float*)out)[(size_t)row * Nout + col] = v;
        } else if constexpr (OUT == 0) {
          ((u16*)out)[(size_t)row * Nout + col] = f2b(v);
        } else {
          const int tt = row >> 8, n = row & 255, mh = col >> 4, d = col & 15;
          ((u16*)out)[(((size_t)tt * 8 + mh) * 256 + n) * 16 + d] = f2b(v);
        }
      }
    }
  }
}

// ---------- attention: 1 block per (t,m); 1 thread per query; zero LDS ----------
// K/V rows are wave-uniform -> scalar (SMEM) loads; chunked online softmax.
__global__ __launch_bounds__(256)
void attn_k(const u16* __restrict__ q, const u16* __restrict__ k,
            const u16* __restrict__ v, u16* __restrict__ ab)
{
  const int tm = blockIdx.x, tt = tm >> 3, m = tm & 7, n = threadIdx.x;

  const u16* qp = q + (size_t)tm * 4096 + n * 16;
  const uint4 qa = *(const uint4*)qp;
  const uint4 qb = *(const uint4*)(qp + 8);
  float qf[16];
  qf[0]=BLO(qa.x); qf[1]=BHI(qa.x); qf[2]=BLO(qa.y); qf[3]=BHI(qa.y);
  qf[4]=BLO(qa.z); qf[5]=BHI(qa.z); qf[6]=BLO(qa.w); qf[7]=BHI(qa.w);
  qf[8]=BLO(qb.x); qf[9]=BHI(qb.x); qf[10]=BLO(qb.y); qf[11]=BHI(qb.y);
  qf[12]=BLO(qb.z); qf[13]=BHI(qb.z); qf[14]=BLO(qb.w); qf[15]=BHI(qb.w);

  const uint4* kp = (const uint4*)(k + (size_t)tm * 4096);  // row j = kp[2j], kp[2j+1]
  const uint4* vp = (const uint4*)(v + (size_t)tm * 4096);

  float acc[16];
#pragma unroll
  for (int d = 0; d < 16; ++d) acc[d] = 0.f;
  float mx = -3.0e38f, ss = 0.f;

  for (int j0 = 0; j0 < 256; j0 += 8) {
    float s[8];
#pragma unroll
    for (int jj = 0; jj < 8; ++jj) {
      const uint4 ka = kp[(j0 + jj) * 2];
      const uint4 kb = kp[(j0 + jj) * 2 + 1];
      float d;
      d  = qf[0]*BLO(ka.x) + qf[1]*BHI(ka.x) + qf[2]*BLO(ka.y) + qf[3]*BHI(ka.y);
      d += qf[4]*BLO(ka.z) + qf[5]*BHI(ka.z) + qf[6]*BLO(ka.w) + qf[7]*BHI(ka.w);
      d += qf[8]*BLO(kb.x) + qf[9]*BHI(kb.x) + qf[10]*BLO(kb.y) + qf[11]*BHI(kb.y);
      d += qf[12]*BLO(kb.z) + qf[13]*BHI(kb.z) + qf[14]*BLO(kb.w) + qf[15]*BHI(kb.w);
      s[jj] = d * 0.25f;   // 1/sqrt(E/M) = 1/4
    }
    float cm = s[0];
#pragma unroll
    for (int jj = 1; jj < 8; ++jj) cm = fmaxf(cm, s[jj]);
    const float nm = fmaxf(mx, cm);
    const float cf = __expf(mx - nm);
    mx = nm;
    ss *= cf;
#pragma unroll
    for (int d = 0; d < 16; ++d) acc[d] *= cf;
#pragma unroll
    for (int jj = 0; jj < 8; ++jj) {
      const float p = __expf(s[jj] - nm);
      ss += p;
      const uint4 va = vp[(j0 + jj) * 2];
      const uint4 vb = vp[(j0 + jj) * 2 + 1];
      acc[0]  = fmaf(p, BLO(va.x), acc[0]);  acc[1]  = fmaf(p, BHI(va.x), acc[1]);
      acc[2]  = fmaf(p, BLO(va.y), acc[2]);  acc[3]  = fmaf(p, BHI(va.y), acc[3]);
      acc[4]  = fmaf(p, BLO(va.z), acc[4]);  acc[5]  = fmaf(p, BHI(va.z), acc[5]);
      acc[6]  = fmaf(p, BLO(va.w), acc[6]);  acc[7]  = fmaf(p, BHI(va.w), acc[7]);
      acc[8]  = fmaf(p, BLO(vb.x), acc[8]);  acc[9]  = fmaf(p, BHI(vb.x), acc[9]);
      acc[10] = fmaf(p, BLO(vb.y), acc[10]); acc[11] = fmaf(p, BHI(vb.y), acc[11]);
      acc[12] = fmaf(p, BLO(vb.z), acc[12]); acc[13] = fmaf(p, BHI(vb.z), acc[13]);
      acc[14] = fmaf(p, BLO(vb.w), acc[14]); acc[15] = fmaf(p, BHI(vb.w), acc[15]);
    }
  }
  const float inv = 1.f / ss;
  u16* op = ab + ((size_t)(tt * 256 + n)) * 128 + m * 16;
  uint4 o0, o1;
  o0.x = (uint32)f2b(acc[0]*inv)  | ((uint32)f2b(acc[1]*inv)  << 16);
  o0.y = (uint32)f2b(acc[2]*inv)  | ((uint32)f2b(acc[3]*inv)  << 16);
  o0.z = (uint32)f2b(acc[4]*inv)  | ((uint32)f2b(acc[5]*inv)  << 16);
  o0.w = (uint32)f2b(acc[6]*inv)  | ((uint32)f2b(acc[7]*inv)  << 16);
  o1.x = (uint32)f2b(acc[8]*inv)  | ((uint32)f2b(acc[9]*inv)  << 16);
  o1.y = (uint32)f2b(acc[10]*inv) | ((uint32)f2b(acc[11]*inv) << 16);
  o1.z = (uint32)f2b(acc[12]*inv) | ((uint32)f2b(acc[13]*inv) << 16);
  o1.w = (uint32)f2b(acc[14]*inv) | ((uint32)f2b(acc[15]*inv) << 16);
  *(uint4*)op = o0;
  *(uint4*)(op + 8) = o1;
}

// ---------- BatchNorm pieces ----------
// partial sums over 256 tokens/block, bf16 input (as uint pairs): x[32768][64] uints
__global__ __launch_bounds__(256)
void stats_partial_b(const uint32* __restrict__ x, float* __restrict__ part)
{
  const int b = blockIdx.x, t = threadIdx.x;
  const int c2 = t & 63, g = t >> 6;
  const uint32* xb = x + (size_t)b * 256 * 64;
  float s0=0,s1=0,q0=0,q1=0;
  for (int r = g; r < 256; r += 4) {
    const uint32 u = xb[(size_t)r * 64 + c2];
    const float a = BLO(u), bb = BHI(u);
    s0 += a; q0 += a*a; s1 += bb; q1 += bb*bb;
  }
  __shared__ float R0[256], R1[256], R2[256], R3[256];
  R0[t]=s0; R1[t]=s1; R2[t]=q0; R3[t]=q1;
  __syncthreads();
  if (t < 64) {
    float a0=0,a1=0,b0=0,b1=0;
#pragma unroll
    for (int gg = 0; gg < 4; ++gg) {
      a0 += R0[gg*64+t]; a1 += R1[gg*64+t]; b0 += R2[gg*64+t]; b1 += R3[gg*64+t];
    }
    part[b*128 + 2*t]           = a0;
    part[b*128 + 2*t + 1]       = a1;
    part[16384 + b*128 + 2*t]     = b0;
    part[16384 + b*128 + 2*t + 1] = b1;
  }
}

// partial sums, fp32 input
__global__ __launch_bounds__(256)
void stats_partial_f(const float* __restrict__ x, float* __restrict__ part)
{
  const int b = blockIdx.x, t = threadIdx.x;
  const int c = t & 127, g = t >> 7;
  const float* xb = x + (size_t)b * 256 * 128;
  float s = 0.f, s2 = 0.f;
  for (int r = g; r < 256; r += 2) {
    const float vv = xb[(size_t)r * 128 + c];
    s += vv; s2 += vv * vv;
  }
  __shared__ float ls[256], ls2[256];
  ls[t] = s; ls2[t] = s2;
  __syncthreads();
  if (t < 128) {
    part[b*128 + t]         = ls[t] + ls[t+128];
    part[16384 + b*128 + t] = ls2[t] + ls2[t+128];
  }
}

__global__ void stats_final(const float* __restrict__ part,
                            const float* __restrict__ gam, const float* __restrict__ bet,
                            float* __restrict__ AB)
{
  const int c = threadIdx.x;  // 128
  float s = 0.f, s2 = 0.f;
  for (int b = 0; b < 128; ++b) { s += part[b*128+c]; s2 += part[16384 + b*128+c]; }
  const float invn = 1.f / 32768.f;
  const float mean = s * invn;
  const float var  = s2 * invn - mean * mean;
  const float rstd = rsqrtf(var + 1e-5f);
  const float Ac = gam[c] * rstd;
  AB[c] = Ac;
  AB[128 + c] = bet[c] - mean * Ac;
}

// bf16 -> bf16 BN apply (x -> y), 1 uint (2 elems) per thread
__global__ __launch_bounds__(256)
void bn_b2b(const uint32* __restrict__ x, const float* __restrict__ AB, uint32* __restrict__ y)
{
  __shared__ float sA[128], sB[128];
  const int t = threadIdx.x;
  if (t < 128) sA[t] = AB[t]; else sB[t-128] = AB[t];
  __syncthreads();
  const size_t i = (size_t)blockIdx.x * 256 + t;
  const uint32 u = x[i];
  const int c = (int)((i * 2) & 127);
  const float a = BLO(u) * sA[c]   + sB[c];
  const float b = BHI(u) * sA[c+1] + sB[c+1];
  y[i] = (uint32)f2b(a) | ((uint32)f2b(b) << 16);
}

// fp32 in-place BN apply (float4 per thread)
__global__ __launch_bounds__(256)
void bn_f32(float* __restrict__ x, const float* __restrict__ AB)
{
  __shared__ float sA[128], sB[128];
  const int t = threadIdx.x;
  if (t < 128) sA[t] = AB[t]; else sB[t-128] = AB[t];
  __syncthreads();
  const size_t i = (size_t)blockIdx.x * 256 + t;
  float4 vv = ((float4*)x)[i];
  const int c = (int)((i * 4) & 127);
  vv.x = vv.x * sA[c]   + sB[c];
  vv.y = vv.y * sA[c+1] + sB[c+1];
  vv.z = vv.z * sA[c+2] + sB[c+2];
  vv.w = vv.w * sA[c+3] + sB[c+3];
  ((float4*)x)[i] = vv;
}

// ---------- launch ----------
extern "C" void kernel_launch(void* const* d_in, const int* in_sizes, int n_in,
                              void* d_out, int out_size, void* d_ws, size_t ws_size,
                              hipStream_t stream)
{
  (void)in_sizes; (void)n_in; (void)out_size; (void)ws_size;
  const float* node = (const float*)d_in[0];
  const float* Wq  = (const float*)d_in[1];  const float* bq  = (const float*)d_in[2];
  const float* Wk  = (const float*)d_in[3];  const float* bk  = (const float*)d_in[4];
  const float* Wv  = (const float*)d_in[5];  const float* bv  = (const float*)d_in[6];
  const float* Ww  = (const float*)d_in[7];  const float* bw  = (const float*)d_in[8];
  const float* Wf1 = (const float*)d_in[9];  const float* bf1 = (const float*)d_in[10];
  const float* Wf2 = (const float*)d_in[11]; const float* bf2 = (const float*)d_in[12];
  const float* g1  = (const float*)d_in[13]; const float* be1 = (const float*)d_in[14];
  const float* g2  = (const float*)d_in[15]; const float* be2 = (const float*)d_in[16];
  float* out = (float*)d_out;
  char* ws = (char*)d_ws;

  // workspace (bytes); peak ~40.6 MB
  u16* nb  = (u16*)(ws + 0);              // node bf16 (8.4 MB) -> later xb (bf16 x)
  u16* wb  = (u16*)(ws + 8388608);        // weights bf16 (0.38 MB)
  u16* qb  = (u16*)(ws + 8912896);        // q bf16 perm -> later xnb
  u16* kb  = (u16*)(ws + 17301504);       // k bf16 perm -> later hb (spans k+v)
  u16* vb  = (u16*)(ws + 25690112);       // v bf16 perm
  u16* ab  = (u16*)(ws + 34078720);       // attn out bf16 (8.4 MB)
  float* AB1  = (float*)(ws + 42467328);
  float* AB2  = (float*)(ws + 42468352);
  float* part = (float*)(ws + 42469376);
  u16* xb  = nb;                          // x (pre-BN1) bf16
  u16* xnb = qb;                          // x after BN1, bf16
  u16* hb  = kb;                          // FFN hidden bf16, 16384x512 per half

  u16* wqb = wb;          u16* wkb = wb + 16384;  u16* wvb = wb + 32768;
  u16* wwb = wb + 49152;  u16* wf1b = wb + 65536; u16* wf2b = wb + 131072;

  dim3 blk(256);

  // 0. fp32 -> bf16 (node + all weights)
  cvt_k<<<dim3(4288), blk, 0, stream>>>((const float4*)node, (const float4*)Wq,
      (const float4*)Wk, (const float4*)Wv, (const float4*)Ww,
      (const float4*)Wf1, (const float4*)Wf2, nb, wb);

  // 1. QKV projections -> bf16 permuted [T][M][N][D]
  gemm_k<2,0,false><<<dim3(256,1), blk, 0, stream>>>(nb, wqb, bq, nullptr, qb, 128, 128);
  gemm_k<2,0,false><<<dim3(256,1), blk, 0, stream>>>(nb, wkb, bk, nullptr, kb, 128, 128);
  gemm_k<2,0,false><<<dim3(256,1), blk, 0, stream>>>(nb, wvb, bv, nullptr, vb, 128, 128);

  // 2. attention
  attn_k<<<dim3(1024), blk, 0, stream>>>(qb, kb, vb, ab);

  // 3. out-proj + node residual -> xb (bf16)
  gemm_k<0,1,false><<<dim3(256,1), blk, 0, stream>>>(ab, wwb, bw, node, xb, 128, 128);

  // 4. BN1: stats on bf16 x, apply -> xnb (bf16)
  stats_partial_b<<<dim3(128), blk, 0, stream>>>((const uint32*)xb, part);
  stats_final<<<dim3(1), dim3(128), 0, stream>>>(part, g1, be1, AB1);
  bn_b2b<<<dim3(8192), blk, 0, stream>>>((const uint32*)xb, AB1, (uint32*)xnb);

  // 5. FFN in two token halves (hidden reuses k/v region)
  for (int half = 0; half < 2; ++half) {
    const size_t ro = (size_t)half * 16384;
    gemm_k<0,0,true><<<dim3(128,4), blk, 0, stream>>>(xnb + ro*128, wf1b, bf1, nullptr, hb, 128, 512);
    gemm_k<1,2,false><<<dim3(128,1), blk, 0, stream>>>(hb, wf2b, bf2, xnb + ro*128,
                                                       out + ro*128, 512, 128);
  }

  // 6. BN2 on d_out (fp32, in place)
  stats_partial_f<<<dim3(128), blk, 0, stream>>>(out, part);
  stats_final<<<dim3(1), dim3(128), 0, stream>>>(part, g2, be2, AB2);
  bn_f32<<<dim3(4096), blk, 0, stream>>>(out, AB2);
}

// Round 3
// 281.328 us; speedup vs baseline: 2.0212x; 1.2877x over previous
//
#include <hip/hip_runtime.h>
#include <stdint.h>

typedef unsigned int  uint32;
typedef unsigned short u16;
typedef __attribute__((ext_vector_type(8))) short short8;
typedef __attribute__((ext_vector_type(4))) float f32x4;
typedef __attribute__((ext_vector_type(4))) _Float16 half4;

// ---------- helpers ----------
__device__ __forceinline__ float bits2f(uint32 u){ union{uint32 u; float f;} c; c.u=u; return c.f; }
__device__ __forceinline__ uint32 f2bits(float f){ union{uint32 u; float f;} c; c.f=f; return c.u; }
__device__ __forceinline__ u16 f2b(float f){ uint32 u=f2bits(f); return (u16)((u + 0x7FFFu + ((u>>16)&1u))>>16); }
__device__ __forceinline__ float b2f(u16 h){ return bits2f(((uint32)h)<<16); }
__device__ __forceinline__ u16 f2h(float f){ _Float16 h=(_Float16)f; union{u16 u; _Float16 h;} c; c.h=h; return c.u; }
__device__ __forceinline__ float4 ld4f(const float* p){ return *(const float4*)p; }
#define BLO(u) bits2f((u)<<16)
#define BHI(u) bits2f((u)&0xFFFF0000u)

// ---------- weights fp32 -> bf16 (6 arrays concatenated), 49152 float4 ----------
__global__ __launch_bounds__(256)
void cvt_w(const float4* __restrict__ wq, const float4* __restrict__ wk,
           const float4* __restrict__ wv, const float4* __restrict__ ww,
           const float4* __restrict__ wf1, const float4* __restrict__ wf2,
           u16* __restrict__ wb)
{
  const int i = blockIdx.x * 256 + threadIdx.x;
  const float4* src;
  if      (i <  4096) src = wq  + i;
  else if (i <  8192) src = wk  + (i-4096);
  else if (i < 12288) src = wv  + (i-8192);
  else if (i < 16384) src = ww  + (i-12288);
  else if (i < 32768) src = wf1 + (i-16384);
  else                src = wf2 + (i-32768);
  float4 v = *src;
  uint2 o;
  o.x = (uint32)f2b(v.x) | ((uint32)f2b(v.y) << 16);
  o.y = (uint32)f2b(v.z) | ((uint32)f2b(v.w) << 16);
  *(uint2*)(wb + (size_t)i*4) = o;
}

// ---------- bf16 MFMA GEMM ----------
// C[row][col] = act(sum_k A[row][k]*W[col][k] + bias[col] (+res))
// 128x128 tile, BK=64, 4 waves (2x2), wave = 4x4 tiles of 16x16x32 mfma.
// OUT: 0 bf16 row-major | 1 f32 row-major | (ISQKV: 2 = f16 [T][M][N][D], 3 = f16 [T][M][D][N])
// RES: 0 none | 1 f32 stride128 | 3 bf16 stride128 with BN affine (bnab)
// AF32: A operand fp32 (convert in staging). BNA: A bf16 with BN affine (bnab).
template<int OUT, int RES, bool RELU, bool AF32, bool BNA, bool ISQKV>
__global__ __launch_bounds__(256)
void gemm_k(const void* __restrict__ Ain,
            const u16* __restrict__ W0, const u16* __restrict__ W1, const u16* __restrict__ W2,
            const float* __restrict__ b0, const float* __restrict__ b1, const float* __restrict__ b2,
            const void* __restrict__ res, const float* __restrict__ bnab,
            void* __restrict__ O0, void* __restrict__ O1, void* __restrict__ O2,
            int K, int Nout, float qscale)
{
  __shared__ u16 As[128*72];
  __shared__ u16 Ws[128*72];
  const int t = threadIdx.x;
  const int row0 = blockIdx.x * 128;

  const u16* W = W0; const float* bias = b0; void* out = O0;
  float oscale = 1.f;
  int omode = OUT, col0 = 0;
  if constexpr (ISQKV) {
    if (blockIdx.y == 1) { W = W1; bias = b1; out = O1; }
    if (blockIdx.y == 2) { W = W2; bias = b2; out = O2; omode = 3; }
    if (blockIdx.y == 0) oscale = qscale;
  } else {
    col0 = blockIdx.y * 128;
  }

  const int L = t & 63, w = t >> 6;
  const int wrow = (w >> 1) * 64, wcol = (w & 1) * 64;
  const int lm = L & 15, lg = L >> 4;

  f32x4 acc[4][4];
#pragma unroll
  for (int i = 0; i < 4; ++i)
#pragma unroll
    for (int j = 0; j < 4; ++j) acc[i][j] = (f32x4){0.f,0.f,0.f,0.f};

  const int srow = t >> 1, skc = (t & 1) * 32;
  const u16* Wp = W + (size_t)(col0 + srow) * K + skc;
  u16* Asp = As + srow * 72 + skc;
  u16* Wsp = Ws + srow * 72 + skc;
  const u16*  Ab = (const u16*)Ain + (size_t)(row0 + srow) * K + skc;
  const float* Af = (const float*)Ain + (size_t)(row0 + srow) * K + skc;

  for (int k0 = 0; k0 < K; k0 += 64) {
    short8 ga[4], gw[4];
    if constexpr (AF32) {
#pragma unroll
      for (int i = 0; i < 4; ++i) {
        const float4 fa = ld4f(Af + k0 + i*8);
        const float4 fb = ld4f(Af + k0 + i*8 + 4);
        short8 s;
        s[0]=(short)f2b(fa.x); s[1]=(short)f2b(fa.y); s[2]=(short)f2b(fa.z); s[3]=(short)f2b(fa.w);
        s[4]=(short)f2b(fb.x); s[5]=(short)f2b(fb.y); s[6]=(short)f2b(fb.z); s[7]=(short)f2b(fb.w);
        ga[i] = s;
      }
    } else if constexpr (BNA) {
#pragma unroll
      for (int i = 0; i < 4; ++i) {
        const int c = k0 + skc + i*8;
        const short8 x8 = *(const short8*)(Ab + k0 + i*8);
        const float4 A0 = ld4f(bnab + c),       A1 = ld4f(bnab + c + 4);
        const float4 B0 = ld4f(bnab + 128 + c), B1 = ld4f(bnab + 128 + c + 4);
        short8 s;
        s[0]=(short)f2b(b2f((u16)x8[0])*A0.x+B0.x); s[1]=(short)f2b(b2f((u16)x8[1])*A0.y+B0.y);
        s[2]=(short)f2b(b2f((u16)x8[2])*A0.z+B0.z); s[3]=(short)f2b(b2f((u16)x8[3])*A0.w+B0.w);
        s[4]=(short)f2b(b2f((u16)x8[4])*A1.x+B1.x); s[5]=(short)f2b(b2f((u16)x8[5])*A1.y+B1.y);
        s[6]=(short)f2b(b2f((u16)x8[6])*A1.z+B1.z); s[7]=(short)f2b(b2f((u16)x8[7])*A1.w+B1.w);
        ga[i] = s;
      }
    } else {
#pragma unroll
      for (int i = 0; i < 4; ++i) ga[i] = *(const short8*)(Ab + k0 + i*8);
    }
#pragma unroll
    for (int i = 0; i < 4; ++i) gw[i] = *(const short8*)(Wp + k0 + i*8);
    __syncthreads();
#pragma unroll
    for (int i = 0; i < 4; ++i) *(short8*)(Asp + i*8) = ga[i];
#pragma unroll
    for (int i = 0; i < 4; ++i) *(short8*)(Wsp + i*8) = gw[i];
    __syncthreads();
#pragma unroll
    for (int ks = 0; ks < 64; ks += 32) {
      short8 af[4], wf[4];
#pragma unroll
      for (int i = 0; i < 4; ++i)
        af[i] = *(const short8*)(As + (wrow + i*16 + lm) * 72 + ks + lg*8);
#pragma unroll
      for (int j = 0; j < 4; ++j)
        wf[j] = *(const short8*)(Ws + (wcol + j*16 + lm) * 72 + ks + lg*8);
#pragma unroll
      for (int i = 0; i < 4; ++i)
#pragma unroll
        for (int j = 0; j < 4; ++j)
          acc[i][j] = __builtin_amdgcn_mfma_f32_16x16x32_bf16(af[i], wf[j], acc[i][j], 0, 0, 0);
    }
  }

  float bj[4];
#pragma unroll
  for (int j = 0; j < 4; ++j) bj[j] = bias[col0 + wcol + j*16 + lm];

#pragma unroll
  for (int i = 0; i < 4; ++i) {
    const int rowb = row0 + wrow + i*16 + lg*4;
#pragma unroll
    for (int j = 0; j < 4; ++j) {
      const int col = col0 + wcol + j*16 + lm;
      float ra = 0.f, rb = 0.f;
      if constexpr (RES == 3) { ra = bnab[col]; rb = bnab[128 + col]; }
      if (omode == 3) {   // f16 [T][M][D][N], 4 consecutive n -> one uint2
        const int tt = rowb >> 8, n0 = rowb & 255;
        const int mh = col >> 4, d = col & 15;
        uint2 o;
        o.x = (uint32)f2h(acc[i][j][0] + bj[j]) | ((uint32)f2h(acc[i][j][1] + bj[j]) << 16);
        o.y = (uint32)f2h(acc[i][j][2] + bj[j]) | ((uint32)f2h(acc[i][j][3] + bj[j]) << 16);
        *(uint2*)((u16*)out + (((size_t)tt*8 + mh)*16 + d)*256 + n0) = o;
      } else {
#pragma unroll
        for (int r = 0; r < 4; ++r) {
          const int row = rowb + r;
          float v = acc[i][j][r] + bj[j];
          if constexpr (RES == 1) v += ((const float*)res)[(size_t)row*128 + col];
          if constexpr (RES == 3) v += b2f(((const u16*)res)[(size_t)row*128 + col]) * ra + rb;
          if constexpr (RELU) v = fmaxf(v, 0.f);
          if (omode == 2) {        // f16 [T][M][N][D], q-scale folded
            const int tt = row >> 8, n = row & 255, mh = col >> 4, d = col & 15;
            ((u16*)out)[(((size_t)tt*8 + mh)*256 + n)*16 + d] = f2h(v * oscale);
          } else if (omode == 1) {
            ((float*)out)[(size_t)row * Nout + col] = v;
          } else {
            ((u16*)out)[(size_t)row * Nout + col] = f2b(v);
          }
        }
      }
    }
  }
}

// ---------- MFMA attention: 1 block per (t,m), 4 waves, f16 16x16x16 MFMA ----------
// q,k: f16 [T][M][N][16] (q pre-scaled by 0.25*log2e); v: f16 [T][M][16][N].
// S^T = K·Q^T (C-layout = A-layout of P), batch softmax in regs, O = P·V. out: bf16 [T][N][E].
#define QKS 24   // Q/K LDS row stride (u16): 16B-aligned, uniform 4-touch banks
__global__ __launch_bounds__(256)
void attn_k(const u16* __restrict__ q, const u16* __restrict__ k,
            const u16* __restrict__ v, u16* __restrict__ ab)
{
  __shared__ __align__(16) u16 Qs[256*QKS];
  __shared__ __align__(16) u16 Ks[256*QKS];
  __shared__ __align__(16) u16 Vt[16*264];
  const int tm = blockIdx.x, tt = tm >> 3, m = tm & 7;
  const int t = threadIdx.x;

  const uint4* qg = (const uint4*)(q + (size_t)tm*4096);
  const uint4* kg = (const uint4*)(k + (size_t)tm*4096);
  const uint4* vg = (const uint4*)(v + (size_t)tm*4096);
#pragma unroll
  for (int p = t; p < 512; p += 256) {
    const uint4 a = qg[p], b = kg[p], c = vg[p];
    const int row = p >> 1, h = (p & 1) * 8;
    *(uint4*)(Qs + row*QKS + h) = a;
    *(uint4*)(Ks + row*QKS + h) = b;
    *(uint4*)(Vt + (p >> 5)*264 + (p & 31)*8) = c;
  }
  __syncthreads();

  const int w = t >> 6, L = t & 63, lm = L & 15, quad = L >> 4;

  half4 vf[16];
#pragma unroll
  for (int jt = 0; jt < 16; ++jt)
    vf[jt] = *(const half4*)(Vt + lm*264 + jt*16 + quad*4);

  for (int nt = 0; nt < 4; ++nt) {
    const half4 bq = *(const half4*)(Qs + ((w*4 + nt)*16 + lm)*QKS + quad*4);
    f32x4 s[16];
#pragma unroll
    for (int jt = 0; jt < 16; ++jt) {
      const half4 af = *(const half4*)(Ks + (jt*16 + lm)*QKS + quad*4);
      s[jt] = __builtin_amdgcn_mfma_f32_16x16x16f16(af, bq, (f32x4){0.f,0.f,0.f,0.f}, 0, 0, 0);
    }
    // softmax over all 256 keys for query (lm): 64 regs + quad reduction
    float mx = s[0][0];
#pragma unroll
    for (int jt = 0; jt < 16; ++jt)
#pragma unroll
      for (int r = 0; r < 4; ++r) mx = fmaxf(mx, s[jt][r]);
    mx = fmaxf(mx, __shfl_xor(mx, 16));
    mx = fmaxf(mx, __shfl_xor(mx, 32));
    float ls = 0.f;
#pragma unroll
    for (int jt = 0; jt < 16; ++jt)
#pragma unroll
      for (int r = 0; r < 4; ++r) { const float p = exp2f(s[jt][r] - mx); s[jt][r] = p; ls += p; }
    ls += __shfl_xor(ls, 16);
    ls += __shfl_xor(ls, 32);

    f32x4 oacc = {0.f,0.f,0.f,0.f};
#pragma unroll
    for (int jt = 0; jt < 16; ++jt) {
      half4 pf;
      pf[0] = (_Float16)s[jt][0]; pf[1] = (_Float16)s[jt][1];
      pf[2] = (_Float16)s[jt][2]; pf[3] = (_Float16)s[jt][3];
      oacc = __builtin_amdgcn_mfma_f32_16x16x16f16(pf, vf[jt], oacc, 0, 0, 0);
    }
    const int q0 = w*64 + nt*16 + quad*4;
#pragma unroll
    for (int r = 0; r < 4; ++r) {
      const float lr = __shfl(ls, quad*4 + r);
      ab[((size_t)tt*256 + q0 + r)*128 + m*16 + lm] = f2b(oacc[r] / lr);
    }
  }
}

// ---------- BatchNorm pieces ----------
__global__ __launch_bounds__(256)
void stats_partial_b(const uint32* __restrict__ x, float* __restrict__ part)
{
  const int b = blockIdx.x, t = threadIdx.x;
  const int c2 = t & 63, g = t >> 6;
  const uint32* xb = x + (size_t)b * 256 * 64;
  float s0=0,s1=0,q0=0,q1=0;
  for (int r = g; r < 256; r += 4) {
    const uint32 u = xb[(size_t)r * 64 + c2];
    const float a = BLO(u), bb = BHI(u);
    s0 += a; q0 += a*a; s1 += bb; q1 += bb*bb;
  }
  __shared__ float R0[256], R1[256], R2[256], R3[256];
  R0[t]=s0; R1[t]=s1; R2[t]=q0; R3[t]=q1;
  __syncthreads();
  if (t < 64) {
    float a0=0,a1=0,b0=0,b1=0;
#pragma unroll
    for (int gg = 0; gg < 4; ++gg) {
      a0 += R0[gg*64+t]; a1 += R1[gg*64+t]; b0 += R2[gg*64+t]; b1 += R3[gg*64+t];
    }
    part[b*128 + 2*t]             = a0;
    part[b*128 + 2*t + 1]         = a1;
    part[16384 + b*128 + 2*t]     = b0;
    part[16384 + b*128 + 2*t + 1] = b1;
  }
}

__global__ __launch_bounds__(256)
void stats_partial_f(const float* __restrict__ x, float* __restrict__ part)
{
  const int b = blockIdx.x, t = threadIdx.x;
  const int c = t & 127, g = t >> 7;
  const float* xb = x + (size_t)b * 256 * 128;
  float s = 0.f, s2 = 0.f;
  for (int r = g; r < 256; r += 2) {
    const float vv = xb[(size_t)r * 128 + c];
    s += vv; s2 += vv * vv;
  }
  __shared__ float ls[256], ls2[256];
  ls[t] = s; ls2[t] = s2;
  __syncthreads();
  if (t < 128) {
    part[b*128 + t]         = ls[t] + ls[t+128];
    part[16384 + b*128 + t] = ls2[t] + ls2[t+128];
  }
}

__global__ void stats_final(const float* __restrict__ part,
                            const float* __restrict__ gam, const float* __restrict__ bet,
                            float* __restrict__ AB)
{
  const int t = threadIdx.x, c = t & 127, h = t >> 7;  // 256 threads
  float s = 0.f, s2 = 0.f;
  for (int b = h*64; b < h*64 + 64; ++b) { s += part[b*128+c]; s2 += part[16384 + b*128+c]; }
  __shared__ float S[256], S2[256];
  S[t] = s; S2[t] = s2;
  __syncthreads();
  if (t < 128) {
    s = S[t] + S[t+128]; s2 = S2[t] + S2[t+128];
    const float invn = 1.f / 32768.f;
    const float mean = s * invn;
    const float var  = s2 * invn - mean * mean;
    const float rstd = rsqrtf(var + 1e-5f);
    const float Ac = gam[c] * rstd;
    AB[c] = Ac;
    AB[128 + c] = bet[c] - mean * Ac;
  }
}

__global__ __launch_bounds__(256)
void bn_f32(float* __restrict__ x, const float* __restrict__ AB)
{
  __shared__ float sA[128], sB[128];
  const int t = threadIdx.x;
  if (t < 128) sA[t] = AB[t]; else sB[t-128] = AB[t];
  __syncthreads();
  const size_t i = (size_t)blockIdx.x * 256 + t;
  float4 vv = ((float4*)x)[i];
  const int c = (int)((i * 4) & 127);
  vv.x = vv.x * sA[c]   + sB[c];
  vv.y = vv.y * sA[c+1] + sB[c+1];
  vv.z = vv.z * sA[c+2] + sB[c+2];
  vv.w = vv.w * sA[c+3] + sB[c+3];
  ((float4*)x)[i] = vv;
}

// ---------- launch ----------
extern "C" void kernel_launch(void* const* d_in, const int* in_sizes, int n_in,
                              void* d_out, int out_size, void* d_ws, size_t ws_size,
                              hipStream_t stream)
{
  (void)in_sizes; (void)n_in; (void)out_size; (void)ws_size;
  const float* node = (const float*)d_in[0];
  const float* Wq  = (const float*)d_in[1];  const float* bq  = (const float*)d_in[2];
  const float* Wk  = (const float*)d_in[3];  const float* bk  = (const float*)d_in[4];
  const float* Wv  = (const float*)d_in[5];  const float* bv  = (const float*)d_in[6];
  const float* Ww  = (const float*)d_in[7];  const float* bw  = (const float*)d_in[8];
  const float* Wf1 = (const float*)d_in[9];  const float* bf1 = (const float*)d_in[10];
  const float* Wf2 = (const float*)d_in[11]; const float* bf2 = (const float*)d_in[12];
  const float* g1  = (const float*)d_in[13]; const float* be1 = (const float*)d_in[14];
  const float* g2  = (const float*)d_in[15]; const float* be2 = (const float*)d_in[16];
  float* out = (float*)d_out;
  char* ws = (char*)d_ws;

  // workspace (bytes); peak ~42.6 MB
  u16* wb  = (u16*)(ws + 0);          // weights bf16 concat (384 KB)
  u16* qb  = (u16*)(ws + 524288);     // q f16 [T][M][N][D]
  u16* kb  = (u16*)(ws + 8912896);    // k f16 [T][M][N][D]
  u16* vb  = (u16*)(ws + 17301504);   // v f16 [T][M][D][N]
  u16* ab  = (u16*)(ws + 25690112);   // attn out bf16 [T][N][E]
  u16* xb  = (u16*)(ws + 34078720);   // x (pre-BN1) bf16
  float* AB1  = (float*)(ws + 42467328);
  float* AB2  = (float*)(ws + 42468352);
  float* part = (float*)(ws + 42469376);
  u16* hb  = qb;                      // FFN hidden bf16 [32768][512] (33.5 MB, reuses q/k/v/ab)

  u16* wqb = wb;          u16* wkb = wb + 16384;  u16* wvb = wb + 32768;
  u16* wwb = wb + 49152;  u16* wf1b = wb + 65536; u16* wf2b = wb + 131072;

  dim3 blk(256);
  const float QSCALE = 0.36067376022224085f;  // 0.25 * log2(e)

  // 0. weights fp32 -> bf16
  cvt_w<<<dim3(192), blk, 0, stream>>>((const float4*)Wq, (const float4*)Wk,
      (const float4*)Wv, (const float4*)Ww, (const float4*)Wf1, (const float4*)Wf2, wb);

  // 1. QKV projections (merged; A=node fp32 converted in staging; f16 perm out)
  gemm_k<2,0,false,true,false,true><<<dim3(256,3), blk, 0, stream>>>(
      node, wqb,wkb,wvb, bq,bk,bv, nullptr, nullptr, qb,kb,vb, 128, 128, QSCALE);

  // 2. attention (MFMA)
  attn_k<<<dim3(1024), blk, 0, stream>>>(qb, kb, vb, ab);

  // 3. out-proj + node residual -> xb (bf16)
  gemm_k<0,1,false,false,false,false><<<dim3(256,1), blk, 0, stream>>>(
      ab, wwb,wwb,wwb, bw,bw,bw, node, nullptr, xb,xb,xb, 128, 128, 1.f);

  // 4. BN1 stats -> AB1 (apply is fused into FFN1 staging / FFN2 residual)
  stats_partial_b<<<dim3(128), blk, 0, stream>>>((const uint32*)xb, part);
  stats_final<<<dim3(1), blk, 0, stream>>>(part, g1, be1, AB1);

  // 5. FFN (full 32768 tokens)
  gemm_k<0,0,true,false,true,false><<<dim3(256,4), blk, 0, stream>>>(
      xb, wf1b,wf1b,wf1b, bf1,bf1,bf1, nullptr, AB1, hb,hb,hb, 128, 512, 1.f);
  gemm_k<1,3,false,false,false,false><<<dim3(256,1), blk, 0, stream>>>(
      hb, wf2b,wf2b,wf2b, bf2,bf2,bf2, xb, AB1, out,out,out, 512, 128, 1.f);

  // 6. BN2 on d_out (fp32, in place)
  stats_partial_f<<<dim3(128), blk, 0, stream>>>(out, part);
  stats_final<<<dim3(1), blk, 0, stream>>>(part, g2, be2, AB2);
  bn_f32<<<dim3(4096), blk, 0, stream>>>(out, AB2);
}

// Round 4
// 225.536 us; speedup vs baseline: 2.5211x; 1.2474x over previous
//
#include <hip/hip_runtime.h>
#include <stdint.h>

typedef unsigned int  uint32;
typedef unsigned short u16;
typedef __attribute__((ext_vector_type(8))) short short8;
typedef __attribute__((ext_vector_type(4))) float f32x4;
typedef __attribute__((ext_vector_type(4))) _Float16 half4;

// ---------- helpers ----------
__device__ __forceinline__ float bits2f(uint32 u){ union{uint32 u; float f;} c; c.u=u; return c.f; }
__device__ __forceinline__ uint32 f2bits(float f){ union{uint32 u; float f;} c; c.f=f; return c.u; }
__device__ __forceinline__ u16 f2b(float f){ uint32 u=f2bits(f); return (u16)((u + 0x7FFFu + ((u>>16)&1u))>>16); }
__device__ __forceinline__ float b2f(u16 h){ return bits2f(((uint32)h)<<16); }
__device__ __forceinline__ u16 f2h(float f){ _Float16 h=(_Float16)f; union{u16 u; _Float16 h;} c; c.h=h; return c.u; }
__device__ __forceinline__ float4 ld4f(const float* p){ return *(const float4*)p; }
#define BLO(u) bits2f((u)<<16)
#define BHI(u) bits2f((u)&0xFFFF0000u)

// ---------- fused bf16 MFMA GEMM ----------
// C[row][col] = act(sum_k A[row][k]*W[col][k] + bias[col] (+res))
// 128x128 tile, BK=64, 4 waves (2x2), wave = 4x4 tiles of 16x16x32 mfma.
// OUT: 0 bf16 row-major | (ISQKV: 2 f16 [T][M][N][D] (*qscale on y==0), y==2 -> 3 f16 [T][M][D][N])
// RES: 0 none | 1 f32 stride128 | 3 bf16 stride128 with BN affine from prologue
// AF32: A fp32 (convert in staging). WF32: W fp32 (convert in staging).
// BNA: apply BN affine (prologue-computed) to A channels during staging (K must be 128).
// STATS: epilogue reduces per-block channel sums/sumsq -> part_out[blk*128+c], [32768+...]
template<int OUT, int RES, bool RELU, bool AF32, bool WF32, bool BNA, bool STATS, bool ISQKV>
__global__ __launch_bounds__(256)
void gemm_k(const void* __restrict__ Ain,
            const void* __restrict__ W0, const void* __restrict__ W1, const void* __restrict__ W2,
            const float* __restrict__ b0, const float* __restrict__ b1, const float* __restrict__ b2,
            const void* __restrict__ res,
            const float* __restrict__ part_in, const float* __restrict__ gam,
            const float* __restrict__ bet, float* __restrict__ part_out,
            void* __restrict__ O0, void* __restrict__ O1, void* __restrict__ O2,
            int K, int Nout, float qscale)
{
  __shared__ u16 As[128*72];
  __shared__ u16 Ws[128*72];
  __shared__ __align__(16) float sA[128], sB[128];
  const int t = threadIdx.x;
  const int row0 = blockIdx.x * 128;

  const void* Wsel = W0; const float* bias = b0; void* out = O0;
  float oscale = 1.f;
  int omode = OUT, col0 = 0;
  if constexpr (ISQKV) {
    if (blockIdx.y == 1) { Wsel = W1; bias = b1; out = O1; }
    if (blockIdx.y == 2) { Wsel = W2; bias = b2; out = O2; omode = 3; }
    if (blockIdx.y == 0) oscale = qscale;
  } else {
    col0 = blockIdx.y * 128;
  }

  // prologue: fold BN stats (per-channel affine) into sA/sB
  if constexpr (BNA || RES == 3) {
    __shared__ float tS[256], tQ[256];
    const int c = t & 127, h = t >> 7;
    float s = 0.f, s2 = 0.f;
#pragma unroll 8
    for (int b = h*128; b < h*128 + 128; ++b) {
      s  += part_in[b*128 + c];
      s2 += part_in[32768 + b*128 + c];
    }
    tS[t] = s; tQ[t] = s2;
    __syncthreads();
    if (t < 128) {
      s = tS[t] + tS[t+128]; s2 = tQ[t] + tQ[t+128];
      const float mean = s * (1.f/32768.f);
      const float var  = s2 * (1.f/32768.f) - mean * mean;
      const float rstd = rsqrtf(var + 1e-5f);
      const float Ac = gam[t] * rstd;
      sA[t] = Ac;
      sB[t] = bet[t] - mean * Ac;
    }
    __syncthreads();
  }

  const int L = t & 63, w = t >> 6;
  const int wrow = (w >> 1) * 64, wcol = (w & 1) * 64;
  const int lm = L & 15, lg = L >> 4;

  f32x4 acc[4][4];
#pragma unroll
  for (int i = 0; i < 4; ++i)
#pragma unroll
    for (int j = 0; j < 4; ++j) acc[i][j] = (f32x4){0.f,0.f,0.f,0.f};

  const int srow = t >> 1, skc = (t & 1) * 32;
  u16* Asp = As + srow * 72 + skc;
  u16* Wsp = Ws + srow * 72 + skc;
  const u16*   Ab  = (const u16*)Ain + (size_t)(row0 + srow) * K + skc;
  const float* Af  = (const float*)Ain + (size_t)(row0 + srow) * K + skc;
  const u16*   Wp16 = (const u16*)Wsel + (size_t)(col0 + srow) * K + skc;
  const float* Wpf  = (const float*)Wsel + (size_t)(col0 + srow) * K + skc;

  for (int k0 = 0; k0 < K; k0 += 64) {
    short8 ga[4], gw[4];
    if constexpr (AF32) {
#pragma unroll
      for (int i = 0; i < 4; ++i) {
        const float4 fa = ld4f(Af + k0 + i*8);
        const float4 fb = ld4f(Af + k0 + i*8 + 4);
        short8 s;
        s[0]=(short)f2b(fa.x); s[1]=(short)f2b(fa.y); s[2]=(short)f2b(fa.z); s[3]=(short)f2b(fa.w);
        s[4]=(short)f2b(fb.x); s[5]=(short)f2b(fb.y); s[6]=(short)f2b(fb.z); s[7]=(short)f2b(fb.w);
        ga[i] = s;
      }
    } else if constexpr (BNA) {
#pragma unroll
      for (int i = 0; i < 4; ++i) {
        const int c = skc + k0 + i*8;  // channel (K==128)
        const short8 x8 = *(const short8*)(Ab + k0 + i*8);
        const float4 A0 = *(const float4*)&sA[c],     A1 = *(const float4*)&sA[c+4];
        const float4 B0 = *(const float4*)&sB[c],     B1 = *(const float4*)&sB[c+4];
        short8 s;
        s[0]=(short)f2b(b2f((u16)x8[0])*A0.x+B0.x); s[1]=(short)f2b(b2f((u16)x8[1])*A0.y+B0.y);
        s[2]=(short)f2b(b2f((u16)x8[2])*A0.z+B0.z); s[3]=(short)f2b(b2f((u16)x8[3])*A0.w+B0.w);
        s[4]=(short)f2b(b2f((u16)x8[4])*A1.x+B1.x); s[5]=(short)f2b(b2f((u16)x8[5])*A1.y+B1.y);
        s[6]=(short)f2b(b2f((u16)x8[6])*A1.z+B1.z); s[7]=(short)f2b(b2f((u16)x8[7])*A1.w+B1.w);
        ga[i] = s;
      }
    } else {
#pragma unroll
      for (int i = 0; i < 4; ++i) ga[i] = *(const short8*)(Ab + k0 + i*8);
    }
    if constexpr (WF32) {
#pragma unroll
      for (int i = 0; i < 4; ++i) {
        const float4 fa = ld4f(Wpf + k0 + i*8);
        const float4 fb = ld4f(Wpf + k0 + i*8 + 4);
        short8 s;
        s[0]=(short)f2b(fa.x); s[1]=(short)f2b(fa.y); s[2]=(short)f2b(fa.z); s[3]=(short)f2b(fa.w);
        s[4]=(short)f2b(fb.x); s[5]=(short)f2b(fb.y); s[6]=(short)f2b(fb.z); s[7]=(short)f2b(fb.w);
        gw[i] = s;
      }
    } else {
#pragma unroll
      for (int i = 0; i < 4; ++i) gw[i] = *(const short8*)(Wp16 + k0 + i*8);
    }
    __syncthreads();
#pragma unroll
    for (int i = 0; i < 4; ++i) *(short8*)(Asp + i*8) = ga[i];
#pragma unroll
    for (int i = 0; i < 4; ++i) *(short8*)(Wsp + i*8) = gw[i];
    __syncthreads();
#pragma unroll
    for (int ks = 0; ks < 64; ks += 32) {
      short8 af[4], wf[4];
#pragma unroll
      for (int i = 0; i < 4; ++i)
        af[i] = *(const short8*)(As + (wrow + i*16 + lm) * 72 + ks + lg*8);
#pragma unroll
      for (int j = 0; j < 4; ++j)
        wf[j] = *(const short8*)(Ws + (wcol + j*16 + lm) * 72 + ks + lg*8);
#pragma unroll
      for (int i = 0; i < 4; ++i)
#pragma unroll
        for (int j = 0; j < 4; ++j)
          acc[i][j] = __builtin_amdgcn_mfma_f32_16x16x32_bf16(af[i], wf[j], acc[i][j], 0, 0, 0);
    }
  }

  float bj[4];
#pragma unroll
  for (int j = 0; j < 4; ++j) bj[j] = bias[col0 + wcol + j*16 + lm];

  float stS[4], stQ[4];  // per-thread channel partials (4 cols)
#pragma unroll
  for (int j = 0; j < 4; ++j) { stS[j] = 0.f; stQ[j] = 0.f; }

#pragma unroll
  for (int i = 0; i < 4; ++i) {
    const int rowb = row0 + wrow + i*16 + lg*4;
#pragma unroll
    for (int j = 0; j < 4; ++j) {
      const int col = col0 + wcol + j*16 + lm;
      float ra = 0.f, rb = 0.f;
      if constexpr (RES == 3) { ra = sA[col & 127]; rb = sB[col & 127]; }
      if (omode == 3) {   // f16 [T][M][D][N]
        const int tt = rowb >> 8, n0 = rowb & 255;
        const int mh = col >> 4, d = col & 15;
        uint2 o;
        o.x = (uint32)f2h(acc[i][j][0] + bj[j]) | ((uint32)f2h(acc[i][j][1] + bj[j]) << 16);
        o.y = (uint32)f2h(acc[i][j][2] + bj[j]) | ((uint32)f2h(acc[i][j][3] + bj[j]) << 16);
        *(uint2*)((u16*)out + (((size_t)tt*8 + mh)*16 + d)*256 + n0) = o;
      } else {
#pragma unroll
        for (int r = 0; r < 4; ++r) {
          const int row = rowb + r;
          float v = acc[i][j][r] + bj[j];
          if constexpr (RES == 1) v += ((const float*)res)[(size_t)row*128 + col];
          if constexpr (RES == 3) v += b2f(((const u16*)res)[(size_t)row*128 + col]) * ra + rb;
          if constexpr (RELU) v = fmaxf(v, 0.f);
          if constexpr (STATS) { stS[j] += v; stQ[j] += v*v; }
          if (omode == 2) {
            const int tt = row >> 8, n = row & 255, mh = col >> 4, d = col & 15;
            ((u16*)out)[(((size_t)tt*8 + mh)*256 + n)*16 + d] = f2h(v * oscale);
          } else {
            ((u16*)out)[(size_t)row * Nout + col] = f2b(v);
          }
        }
      }
    }
  }

  if constexpr (STATS) {
    __shared__ float pS[128], pQ[128];
    if (t < 128) { pS[t] = 0.f; pQ[t] = 0.f; }
    __syncthreads();
#pragma unroll
    for (int j = 0; j < 4; ++j) {
      const int col = wcol + j*16 + lm;   // col0 == 0 for STATS users
      atomicAdd(&pS[col], stS[j]);
      atomicAdd(&pQ[col], stQ[j]);
    }
    __syncthreads();
    if (t < 128) {
      part_out[(size_t)blockIdx.x * 128 + t]          = pS[t];
      part_out[32768 + (size_t)blockIdx.x * 128 + t]  = pQ[t];
    }
  }
}

// ---------- MFMA attention: 1 block per (t,m), 4 waves, f16 16x16x16 MFMA ----------
#define QKS 24
__global__ __launch_bounds__(256)
void attn_k(const u16* __restrict__ q, const u16* __restrict__ k,
            const u16* __restrict__ v, u16* __restrict__ ab)
{
  __shared__ __align__(16) u16 Qs[256*QKS];
  __shared__ __align__(16) u16 Ks[256*QKS];
  __shared__ __align__(16) u16 Vt[16*264];
  const int tm = blockIdx.x, tt = tm >> 3, m = tm & 7;
  const int t = threadIdx.x;

  const uint4* qg = (const uint4*)(q + (size_t)tm*4096);
  const uint4* kg = (const uint4*)(k + (size_t)tm*4096);
  const uint4* vg = (const uint4*)(v + (size_t)tm*4096);
#pragma unroll
  for (int p = t; p < 512; p += 256) {
    const uint4 a = qg[p], b = kg[p], c = vg[p];
    const int row = p >> 1, h = (p & 1) * 8;
    *(uint4*)(Qs + row*QKS + h) = a;
    *(uint4*)(Ks + row*QKS + h) = b;
    *(uint4*)(Vt + (p >> 5)*264 + (p & 31)*8) = c;
  }
  __syncthreads();

  const int w = t >> 6, L = t & 63, lm = L & 15, quad = L >> 4;

  half4 vf[16];
#pragma unroll
  for (int jt = 0; jt < 16; ++jt)
    vf[jt] = *(const half4*)(Vt + lm*264 + jt*16 + quad*4);

  for (int nt = 0; nt < 4; ++nt) {
    const half4 bq = *(const half4*)(Qs + ((w*4 + nt)*16 + lm)*QKS + quad*4);
    f32x4 s[16];
#pragma unroll
    for (int jt = 0; jt < 16; ++jt) {
      const half4 af = *(const half4*)(Ks + (jt*16 + lm)*QKS + quad*4);
      s[jt] = __builtin_amdgcn_mfma_f32_16x16x16f16(af, bq, (f32x4){0.f,0.f,0.f,0.f}, 0, 0, 0);
    }
    float mx = s[0][0];
#pragma unroll
    for (int jt = 0; jt < 16; ++jt)
#pragma unroll
      for (int r = 0; r < 4; ++r) mx = fmaxf(mx, s[jt][r]);
    mx = fmaxf(mx, __shfl_xor(mx, 16));
    mx = fmaxf(mx, __shfl_xor(mx, 32));
    float ls = 0.f;
#pragma unroll
    for (int jt = 0; jt < 16; ++jt)
#pragma unroll
      for (int r = 0; r < 4; ++r) { const float p = exp2f(s[jt][r] - mx); s[jt][r] = p; ls += p; }
    ls += __shfl_xor(ls, 16);
    ls += __shfl_xor(ls, 32);

    f32x4 oacc = {0.f,0.f,0.f,0.f};
#pragma unroll
    for (int jt = 0; jt < 16; ++jt) {
      half4 pf;
      pf[0] = (_Float16)s[jt][0]; pf[1] = (_Float16)s[jt][1];
      pf[2] = (_Float16)s[jt][2]; pf[3] = (_Float16)s[jt][3];
      oacc = __builtin_amdgcn_mfma_f32_16x16x16f16(pf, vf[jt], oacc, 0, 0, 0);
    }
    const int q0 = w*64 + nt*16 + quad*4;
#pragma unroll
    for (int r = 0; r < 4; ++r) {
      const float lr = __shfl(ls, quad*4 + r);
      ab[((size_t)tt*256 + q0 + r)*128 + m*16 + lm] = f2b(oacc[r] / lr);
    }
  }
}

// ---------- final: AB2 prologue + BN apply bf16 x2 -> fp32 out ----------
__global__ __launch_bounds__(256)
void bn_final(const uint32* __restrict__ x2, const float* __restrict__ part,
              const float* __restrict__ gam, const float* __restrict__ bet,
              float* __restrict__ out)
{
  __shared__ float sA[128], sB[128];
  {
    __shared__ float tS[256], tQ[256];
    const int t = threadIdx.x, c = t & 127, h = t >> 7;
    float s = 0.f, s2 = 0.f;
#pragma unroll 8
    for (int b = h*128; b < h*128 + 128; ++b) {
      s  += part[b*128 + c];
      s2 += part[32768 + b*128 + c];
    }
    tS[t] = s; tQ[t] = s2;
    __syncthreads();
    if (t < 128) {
      s = tS[t] + tS[t+128]; s2 = tQ[t] + tQ[t+128];
      const float mean = s * (1.f/32768.f);
      const float var  = s2 * (1.f/32768.f) - mean * mean;
      const float rstd = rsqrtf(var + 1e-5f);
      const float Ac = gam[t] * rstd;
      sA[t] = Ac;
      sB[t] = bet[t] - mean * Ac;
    }
    __syncthreads();
  }
  const int t = threadIdx.x;
#pragma unroll 4
  for (int k = 0; k < 32; ++k) {
    const size_t idx = (size_t)blockIdx.x * 8192 + k * 256 + t;
    const uint32 u = x2[idx];
    const int c = (int)((idx & 63) * 2);
    float2 o;
    o.x = BLO(u) * sA[c]   + sB[c];
    o.y = BHI(u) * sA[c+1] + sB[c+1];
    ((float2*)out)[idx] = o;
  }
}

// ---------- launch ----------
extern "C" void kernel_launch(void* const* d_in, const int* in_sizes, int n_in,
                              void* d_out, int out_size, void* d_ws, size_t ws_size,
                              hipStream_t stream)
{
  (void)in_sizes; (void)n_in; (void)out_size; (void)ws_size;
  const float* node = (const float*)d_in[0];
  const float* Wq  = (const float*)d_in[1];  const float* bq  = (const float*)d_in[2];
  const float* Wk  = (const float*)d_in[3];  const float* bk  = (const float*)d_in[4];
  const float* Wv  = (const float*)d_in[5];  const float* bv  = (const float*)d_in[6];
  const float* Ww  = (const float*)d_in[7];  const float* bw  = (const float*)d_in[8];
  const float* Wf1 = (const float*)d_in[9];  const float* bf1 = (const float*)d_in[10];
  const float* Wf2 = (const float*)d_in[11]; const float* bf2 = (const float*)d_in[12];
  const float* g1  = (const float*)d_in[13]; const float* be1 = (const float*)d_in[14];
  const float* g2  = (const float*)d_in[15]; const float* be2 = (const float*)d_in[16];
  float* out = (float*)d_out;
  char* ws = (char*)d_ws;

  // workspace (bytes); peak ~50.9 MB
  u16* qb  = (u16*)(ws + 0);           // q f16 [T][M][N][D]
  u16* kb  = (u16*)(ws + 8388608);     // k f16 [T][M][N][D]
  u16* vb  = (u16*)(ws + 16777216);    // v f16 [T][M][D][N]
  u16* ab  = (u16*)(ws + 25165824);    // attn out bf16 [T][N][E]
  u16* xb  = (u16*)(ws + 33554432);    // x (pre-BN1) bf16
  u16* x2b = (u16*)(ws + 41943040);    // x2 (pre-BN2) bf16
  float* part1 = (float*)(ws + 50331648);  // 256 blk x 128 ch x {sum,sumsq}
  float* part2 = (float*)(ws + 50593792);
  u16* hb = qb;                        // FFN hidden bf16 [32768][512], reuses q/k/v/ab

  dim3 blk(256);
  const float QSCALE = 0.36067376022224085f;  // 0.25 * log2(e)

  // 1. QKV projections (A=node fp32, W fp32 converted in staging; f16 perm out)
  gemm_k<2,0,false,true,true,false,false,true><<<dim3(256,3), blk, 0, stream>>>(
      node, Wq,Wk,Wv, bq,bk,bv, nullptr, nullptr,nullptr,nullptr,nullptr,
      qb,kb,vb, 128, 128, QSCALE);

  // 2. attention (MFMA)
  attn_k<<<dim3(1024), blk, 0, stream>>>(qb, kb, vb, ab);

  // 3. out-proj + node residual -> xb (bf16), BN1 partials in epilogue
  gemm_k<0,1,false,false,true,false,true,false><<<dim3(256,1), blk, 0, stream>>>(
      ab, Ww,Ww,Ww, bw,bw,bw, node, nullptr,nullptr,nullptr, part1,
      xb,xb,xb, 128, 128, 1.f);

  // 4. FFN1: BN1 affine fused into A-staging (prologue computes AB1 from part1)
  gemm_k<0,0,true,false,true,true,false,false><<<dim3(256,4), blk, 0, stream>>>(
      xb, Wf1,Wf1,Wf1, bf1,bf1,bf1, nullptr, part1,g1,be1, nullptr,
      hb,hb,hb, 128, 512, 1.f);

  // 5. FFN2 + BN1(xb) residual -> x2 (bf16), BN2 partials in epilogue
  gemm_k<0,3,false,false,true,false,true,false><<<dim3(256,1), blk, 0, stream>>>(
      hb, Wf2,Wf2,Wf2, bf2,bf2,bf2, xb, part1,g1,be1, part2,
      x2b,x2b,x2b, 512, 128, 1.f);

  // 6. BN2 apply -> fp32 out
  bn_final<<<dim3(256), blk, 0, stream>>>((const uint32*)x2b, part2, g2, be2, out);
}

// Round 6
// 208.964 us; speedup vs baseline: 2.7211x; 1.0793x over previous
//
#include <hip/hip_runtime.h>
#include <stdint.h>

typedef unsigned int  uint32;
typedef unsigned short u16;
typedef __attribute__((ext_vector_type(8))) short short8;
typedef __attribute__((ext_vector_type(4))) float f32x4;
typedef __attribute__((ext_vector_type(4))) _Float16 half4;

// ---------- helpers ----------
__device__ __forceinline__ float bits2f(uint32 u){ union{uint32 u; float f;} c; c.u=u; return c.f; }
__device__ __forceinline__ uint32 f2bits(float f){ union{uint32 u; float f;} c; c.f=f; return c.u; }
__device__ __forceinline__ u16 f2b(float f){ uint32 u=f2bits(f); return (u16)((u + 0x7FFFu + ((u>>16)&1u))>>16); }
__device__ __forceinline__ float b2f(u16 h){ return bits2f(((uint32)h)<<16); }
__device__ __forceinline__ u16 f2h(float f){ _Float16 h=(_Float16)f; union{u16 u; _Float16 h;} c; c.h=h; return c.u; }
__device__ __forceinline__ float4 ld4f(const float* p){ return *(const float4*)p; }
#define BLO(u) bits2f((u)<<16)
#define BHI(u) bits2f((u)&0xFFFF0000u)

// ---------- weights fp32 -> bf16 (6 arrays concat), 49152 float4 ----------
__global__ __launch_bounds__(256)
void cvt_w(const float4* __restrict__ wq, const float4* __restrict__ wk,
           const float4* __restrict__ wv, const float4* __restrict__ ww,
           const float4* __restrict__ wf1, const float4* __restrict__ wf2,
           u16* __restrict__ wb)
{
  const int i = blockIdx.x * 256 + threadIdx.x;
  const float4* src;
  if      (i <  4096) src = wq  + i;
  else if (i <  8192) src = wk  + (i-4096);
  else if (i < 12288) src = wv  + (i-8192);
  else if (i < 16384) src = ww  + (i-12288);
  else if (i < 32768) src = wf1 + (i-16384);
  else                src = wf2 + (i-32768);
  float4 v = *src;
  uint2 o;
  o.x = (uint32)f2b(v.x) | ((uint32)f2b(v.y) << 16);
  o.y = (uint32)f2b(v.z) | ((uint32)f2b(v.w) << 16);
  *(uint2*)(wb + (size_t)i*4) = o;
}

// ---------- fold raw BN sums into per-channel affine in LDS ----------
__device__ __forceinline__ void load_ab(const float* __restrict__ gacc,
                                        const float* __restrict__ gam,
                                        const float* __restrict__ bet,
                                        float* sA, float* sB, int t)
{
  if (t < 128) {
    const float mean = gacc[t] * (1.f/32768.f);
    const float var  = gacc[128 + t] * (1.f/32768.f) - mean * mean;
    const float rstd = rsqrtf(var + 1e-5f);
    const float Ac = gam[t] * rstd;
    sA[t] = Ac;
    sB[t] = bet[t] - mean * Ac;
  }
  __syncthreads();
}

// ---------- bf16 MFMA GEMM ----------
// C[row][col] = act(sum_k A[row][k]*W[col][k] + bias[col] (+res))
// 128 x (JT*32) tile, BK=64, 4 waves, wave = 4 x JT tiles of 16x16x32 mfma.
// OMODE: 0 bf16 row-major | 2 f16 [T][M][N][D] (*oscale) | 3 f16 [T][M][D][N] (V)
// RES: 0 none | 1 f32 stride128 | 3 bf16 stride128 with BN affine (sA/sB)
// AF32: A fp32, convert in staging. BNA: BN affine on A channels (K==128).
// STATS: epilogue channel sums -> global atomics gacc_out[c], [128+c] (Nout==128).
template<int OMODE, int RES, bool RELU, bool AF32, bool BNA, bool STATS, bool ISQKV, int JT>
__global__ __launch_bounds__(256)
void gemm_k(const void* __restrict__ Ain,
            const u16* __restrict__ W0, const u16* __restrict__ W1, const u16* __restrict__ W2,
            const float* __restrict__ b0, const float* __restrict__ b1, const float* __restrict__ b2,
            const void* __restrict__ res,
            const float* __restrict__ gacc_in, const float* __restrict__ gam,
            const float* __restrict__ bet, float* __restrict__ gacc_out,
            void* __restrict__ O0, void* __restrict__ O1, void* __restrict__ O2,
            int K, int Nout, float qscale)
{
  constexpr int WROWS = JT * 32;           // W rows (= block col coverage)
  __shared__ u16 As[128*72];
  __shared__ u16 Ws[WROWS*72];
  __shared__ __align__(16) float sA[128], sB[128];
  __shared__ float pS[128], pQ[128];
  const int t = threadIdx.x;
  const int row0 = blockIdx.x * 128;

  const u16* W = W0; const float* bias = b0; void* out = O0;
  float oscale = 1.f;
  int omode = OMODE, col0 = 0;
  if constexpr (ISQKV) {
    if (blockIdx.y == 1) { W = W1; bias = b1; out = O1; }
    if (blockIdx.y == 2) { W = W2; bias = b2; out = O2; omode = 3; }
    if (blockIdx.y == 0) oscale = qscale;
  } else {
    col0 = blockIdx.y * WROWS;
  }

  if constexpr (BNA || RES == 3) load_ab(gacc_in, gam, bet, sA, sB, t);

  const int L = t & 63, w = t >> 6;
  const int wrow = (w >> 1) * 64, wcol = (w & 1) * (JT * 16);
  const int lm = L & 15, lg = L >> 4;

  f32x4 acc[4][JT];
#pragma unroll
  for (int i = 0; i < 4; ++i)
#pragma unroll
    for (int j = 0; j < JT; ++j) acc[i][j] = (f32x4){0.f,0.f,0.f,0.f};

  // A staging: 128 rows, 2 threads/row, 32 halfwords each
  const int srow = t >> 1, skc = (t & 1) * 32;
  const u16*   Ab = (const u16*)Ain + (size_t)(row0 + srow) * K + skc;
  const float* Af = (const float*)Ain + (size_t)(row0 + srow) * K + skc;
  u16* Asp = As + srow * 72 + skc;
  // W staging: WROWS rows
  constexpr int TPR = 256 / WROWS;             // threads per W row (2 or 4)
  const int wsrow = t / TPR, wskc = (t % TPR) * (64 / TPR);
  const u16* Wp = W + (size_t)(col0 + wsrow) * K + wskc;
  u16* Wsp = Ws + wsrow * 72 + wskc;
  constexpr int NW = (64 / TPR) / 8;           // short8 chunks per thread (4 or 2)

  for (int k0 = 0; k0 < K; k0 += 64) {
    short8 ga[4], gw[NW];
    if constexpr (AF32) {
#pragma unroll
      for (int i = 0; i < 4; ++i) {
        const float4 fa = ld4f(Af + k0 + i*8);
        const float4 fb = ld4f(Af + k0 + i*8 + 4);
        short8 s;
        s[0]=(short)f2b(fa.x); s[1]=(short)f2b(fa.y); s[2]=(short)f2b(fa.z); s[3]=(short)f2b(fa.w);
        s[4]=(short)f2b(fb.x); s[5]=(short)f2b(fb.y); s[6]=(short)f2b(fb.z); s[7]=(short)f2b(fb.w);
        ga[i] = s;
      }
    } else if constexpr (BNA) {
#pragma unroll
      for (int i = 0; i < 4; ++i) {
        const int c = skc + k0 + i*8;   // channel (K == 128)
        const short8 x8 = *(const short8*)(Ab + k0 + i*8);
        const float4 A0 = *(const float4*)&sA[c], A1 = *(const float4*)&sA[c+4];
        const float4 B0 = *(const float4*)&sB[c], B1 = *(const float4*)&sB[c+4];
        short8 s;
        s[0]=(short)f2b(b2f((u16)x8[0])*A0.x+B0.x); s[1]=(short)f2b(b2f((u16)x8[1])*A0.y+B0.y);
        s[2]=(short)f2b(b2f((u16)x8[2])*A0.z+B0.z); s[3]=(short)f2b(b2f((u16)x8[3])*A0.w+B0.w);
        s[4]=(short)f2b(b2f((u16)x8[4])*A1.x+B1.x); s[5]=(short)f2b(b2f((u16)x8[5])*A1.y+B1.y);
        s[6]=(short)f2b(b2f((u16)x8[6])*A1.z+B1.z); s[7]=(short)f2b(b2f((u16)x8[7])*A1.w+B1.w);
        ga[i] = s;
      }
    } else {
#pragma unroll
      for (int i = 0; i < 4; ++i) ga[i] = *(const short8*)(Ab + k0 + i*8);
    }
#pragma unroll
    for (int i = 0; i < NW; ++i) gw[i] = *(const short8*)(Wp + k0 + i*8);
    __syncthreads();   // previous chunk fully consumed
#pragma unroll
    for (int i = 0; i < 4; ++i) *(short8*)(Asp + i*8) = ga[i];
#pragma unroll
    for (int i = 0; i < NW; ++i) *(short8*)(Wsp + i*8) = gw[i];
    __syncthreads();
#pragma unroll
    for (int ks = 0; ks < 64; ks += 32) {
      short8 af[4], wf[JT];
#pragma unroll
      for (int i = 0; i < 4; ++i)
        af[i] = *(const short8*)(As + (wrow + i*16 + lm) * 72 + ks + lg*8);
#pragma unroll
      for (int j = 0; j < JT; ++j)
        wf[j] = *(const short8*)(Ws + (wcol + j*16 + lm) * 72 + ks + lg*8);
#pragma unroll
      for (int i = 0; i < 4; ++i)
#pragma unroll
        for (int j = 0; j < JT; ++j)
          acc[i][j] = __builtin_amdgcn_mfma_f32_16x16x32_bf16(af[i], wf[j], acc[i][j], 0, 0, 0);
    }
  }

  float bj[JT];
#pragma unroll
  for (int j = 0; j < JT; ++j) bj[j] = bias[col0 + wcol + j*16 + lm];

  float stS[JT], stQ[JT];
#pragma unroll
  for (int j = 0; j < JT; ++j) { stS[j] = 0.f; stQ[j] = 0.f; }

#pragma unroll
  for (int i = 0; i < 4; ++i) {
    const int rowb = row0 + wrow + i*16 + lg*4;
#pragma unroll
    for (int j = 0; j < JT; ++j) {
      const int col = col0 + wcol + j*16 + lm;
      float ra = 0.f, rb = 0.f;
      if constexpr (RES == 3) { ra = sA[col & 127]; rb = sB[col & 127]; }
      if (omode == 3) {   // f16 [T][M][D][N]
        const int tt = rowb >> 8, n0 = rowb & 255;
        const int mh = col >> 4, d = col & 15;
        uint2 o;
        o.x = (uint32)f2h(acc[i][j][0] + bj[j]) | ((uint32)f2h(acc[i][j][1] + bj[j]) << 16);
        o.y = (uint32)f2h(acc[i][j][2] + bj[j]) | ((uint32)f2h(acc[i][j][3] + bj[j]) << 16);
        *(uint2*)((u16*)out + (((size_t)tt*8 + mh)*16 + d)*256 + n0) = o;
      } else {
#pragma unroll
        for (int r = 0; r < 4; ++r) {
          const int row = rowb + r;
          float v = acc[i][j][r] + bj[j];
          if constexpr (RES == 1) v += ((const float*)res)[(size_t)row*128 + col];
          if constexpr (RES == 3) v += b2f(((const u16*)res)[(size_t)row*128 + col]) * ra + rb;
          if constexpr (RELU) v = fmaxf(v, 0.f);
          if constexpr (STATS) { stS[j] += v; stQ[j] += v*v; }
          if (omode == 2) {
            const int tt = row >> 8, n = row & 255, mh = col >> 4, d = col & 15;
            ((u16*)out)[(((size_t)tt*8 + mh)*256 + n)*16 + d] = f2h(v * oscale);
          } else {
            ((u16*)out)[(size_t)row * Nout + col] = f2b(v);
          }
        }
      }
    }
  }

  if constexpr (STATS) {   // Nout == 128; col0+wcol+j*16+lm < 128
    __syncthreads();
    if (t < 128) { pS[t] = 0.f; pQ[t] = 0.f; }
    __syncthreads();
#pragma unroll
    for (int j = 0; j < JT; ++j) {
      const int col = col0 + wcol + j*16 + lm;
      atomicAdd(&pS[col], stS[j]);
      atomicAdd(&pQ[col], stQ[j]);
    }
    __syncthreads();
    if (t < 128) {
      atomicAdd(&gacc_out[t],       pS[t]);
      atomicAdd(&gacc_out[128 + t], pQ[t]);
    }
  }
}

// ---------- MFMA attention: 1 block per (t,m), 4 waves, f16 16x16x16 MFMA ----------
#define QKS 24
__global__ __launch_bounds__(256)
void attn_k(const u16* __restrict__ q, const u16* __restrict__ k,
            const u16* __restrict__ v, u16* __restrict__ ab)
{
  __shared__ __align__(16) u16 Qs[256*QKS];
  __shared__ __align__(16) u16 Ks[256*QKS];
  __shared__ __align__(16) u16 Vt[16*264];
  const int tm = blockIdx.x, tt = tm >> 3, m = tm & 7;
  const int t = threadIdx.x;

  const uint4* qg = (const uint4*)(q + (size_t)tm*4096);
  const uint4* kg = (const uint4*)(k + (size_t)tm*4096);
  const uint4* vg = (const uint4*)(v + (size_t)tm*4096);
#pragma unroll
  for (int p = t; p < 512; p += 256) {
    const uint4 a = qg[p], b = kg[p], c = vg[p];
    const int row = p >> 1, h = (p & 1) * 8;
    *(uint4*)(Qs + row*QKS + h) = a;
    *(uint4*)(Ks + row*QKS + h) = b;
    *(uint4*)(Vt + (p >> 5)*264 + (p & 31)*8) = c;
  }
  __syncthreads();

  const int w = t >> 6, L = t & 63, lm = L & 15, quad = L >> 4;

  half4 vf[16];
#pragma unroll
  for (int jt = 0; jt < 16; ++jt)
    vf[jt] = *(const half4*)(Vt + lm*264 + jt*16 + quad*4);

  for (int nt = 0; nt < 4; ++nt) {
    const half4 bq = *(const half4*)(Qs + ((w*4 + nt)*16 + lm)*QKS + quad*4);
    f32x4 s[16];
#pragma unroll
    for (int jt = 0; jt < 16; ++jt) {
      const half4 af = *(const half4*)(Ks + (jt*16 + lm)*QKS + quad*4);
      s[jt] = __builtin_amdgcn_mfma_f32_16x16x16f16(af, bq, (f32x4){0.f,0.f,0.f,0.f}, 0, 0, 0);
    }
    float mx = s[0][0];
#pragma unroll
    for (int jt = 0; jt < 16; ++jt)
#pragma unroll
      for (int r = 0; r < 4; ++r) mx = fmaxf(mx, s[jt][r]);
    mx = fmaxf(mx, __shfl_xor(mx, 16));
    mx = fmaxf(mx, __shfl_xor(mx, 32));
    float ls = 0.f;
#pragma unroll
    for (int jt = 0; jt < 16; ++jt)
#pragma unroll
      for (int r = 0; r < 4; ++r) { const float p = exp2f(s[jt][r] - mx); s[jt][r] = p; ls += p; }
    ls += __shfl_xor(ls, 16);
    ls += __shfl_xor(ls, 32);

    f32x4 oacc = {0.f,0.f,0.f,0.f};
#pragma unroll
    for (int jt = 0; jt < 16; ++jt) {
      half4 pf;
      pf[0] = (_Float16)s[jt][0]; pf[1] = (_Float16)s[jt][1];
      pf[2] = (_Float16)s[jt][2]; pf[3] = (_Float16)s[jt][3];
      oacc = __builtin_amdgcn_mfma_f32_16x16x16f16(pf, vf[jt], oacc, 0, 0, 0);
    }
    const int q0 = w*64 + nt*16 + quad*4;
#pragma unroll
    for (int r = 0; r < 4; ++r) {
      const float lr = __shfl(ls, quad*4 + r);
      ab[((size_t)tt*256 + q0 + r)*128 + m*16 + lm] = f2b(oacc[r] / lr);
    }
  }
}

// ---------- final: BN2 affine from gacc + apply bf16 -> fp32 out ----------
__global__ __launch_bounds__(256)
void bn_final(const uint32* __restrict__ x2, const float* __restrict__ gacc,
              const float* __restrict__ gam, const float* __restrict__ bet,
              float* __restrict__ out)
{
  __shared__ float sA[128], sB[128];
  const int t = threadIdx.x;
  load_ab(gacc, gam, bet, sA, sB, t);
#pragma unroll 4
  for (int kk = 0; kk < 32; ++kk) {
    const size_t idx = (size_t)blockIdx.x * 8192 + kk * 256 + t;
    const uint32 u = x2[idx];
    const int c = (int)((idx & 63) * 2);
    float2 o;
    o.x = BLO(u) * sA[c]   + sB[c];
    o.y = BHI(u) * sA[c+1] + sB[c+1];
    ((float2*)out)[idx] = o;
  }
}

// ---------- launch ----------
extern "C" void kernel_launch(void* const* d_in, const int* in_sizes, int n_in,
                              void* d_out, int out_size, void* d_ws, size_t ws_size,
                              hipStream_t stream)
{
  (void)in_sizes; (void)n_in; (void)out_size; (void)ws_size;
  const float* node = (const float*)d_in[0];
  const float* Wq  = (const float*)d_in[1];  const float* bq  = (const float*)d_in[2];
  const float* Wk  = (const float*)d_in[3];  const float* bk  = (const float*)d_in[4];
  const float* Wv  = (const float*)d_in[5];  const float* bv  = (const float*)d_in[6];
  const float* Ww  = (const float*)d_in[7];  const float* bw  = (const float*)d_in[8];
  const float* Wf1 = (const float*)d_in[9];  const float* bf1 = (const float*)d_in[10];
  const float* Wf2 = (const float*)d_in[11]; const float* bf2 = (const float*)d_in[12];
  const float* g1  = (const float*)d_in[13]; const float* be1 = (const float*)d_in[14];
  const float* g2  = (const float*)d_in[15]; const float* be2 = (const float*)d_in[16];
  float* out = (float*)d_out;
  char* ws = (char*)d_ws;

  // workspace (bytes); peak ~51.3 MB
  u16* wb  = (u16*)(ws + 0);          // weights bf16 concat (384 KB)
  u16* qb  = (u16*)(ws + 524288);     // q f16 [T][M][N][D] (pre-scaled)
  u16* kb  = (u16*)(ws + 8912896);    // k f16 [T][M][N][D]
  u16* vb  = (u16*)(ws + 17301504);   // v f16 [T][M][D][N]
  u16* ab  = (u16*)(ws + 25690112);   // attn out bf16 [T][N][E]
  u16* xb  = (u16*)(ws + 34078720);   // x (pre-BN1) bf16
  u16* x2b = (u16*)(ws + 42467328);   // x2 (pre-BN2) bf16
  float* accbuf = (float*)(ws + 50855936);  // 512 floats: sum1,sq1,sum2,sq2
  u16* hb  = qb;                      // FFN hidden bf16 [32768][512], reuses q/k/v/ab

  u16* wqb = wb;          u16* wkb = wb + 16384;  u16* wvb = wb + 32768;
  u16* wwb = wb + 49152;  u16* wf1b = wb + 65536; u16* wf2b = wb + 131072;

  dim3 blk(256);
  const float QSCALE = 0.36067376022224085f;  // 0.25 * log2(e)

  // 0. zero BN accumulators + weights fp32 -> bf16
  hipMemsetAsync(accbuf, 0, 512 * sizeof(float), stream);
  cvt_w<<<dim3(192), blk, 0, stream>>>((const float4*)Wq, (const float4*)Wk,
      (const float4*)Wv, (const float4*)Ww, (const float4*)Wf1, (const float4*)Wf2, wb);

  // 1. QKV projections (A=node fp32 converted in staging; f16 perm out)
  gemm_k<2,0,false,true,false,false,true,4><<<dim3(256,3), blk, 0, stream>>>(
      node, wqb,wkb,wvb, bq,bk,bv, nullptr, nullptr,nullptr,nullptr,nullptr,
      qb,kb,vb, 128, 128, QSCALE);

  // 2. attention
  attn_k<<<dim3(1024), blk, 0, stream>>>(qb, kb, vb, ab);

  // 3. out-proj + node residual -> xb (bf16), BN1 sums -> accbuf[0..256)
  gemm_k<0,1,false,false,false,true,false,4><<<dim3(256,1), blk, 0, stream>>>(
      ab, wwb,wwb,wwb, bw,bw,bw, node, nullptr,nullptr,nullptr, accbuf,
      xb,xb,xb, 128, 128, 1.f);

  // 4. FFN1: BN1 affine folded into A staging (prologue from accbuf)
  gemm_k<0,0,true,false,true,false,false,4><<<dim3(256,4), blk, 0, stream>>>(
      xb, wf1b,wf1b,wf1b, bf1,bf1,bf1, nullptr, accbuf,g1,be1, nullptr,
      hb,hb,hb, 128, 512, 1.f);

  // 5. FFN2 (128x64 tiles, 512 blocks) + BN1(xb) residual -> x2b, BN2 sums -> accbuf[256..)
  gemm_k<0,3,false,false,false,true,false,2><<<dim3(256,2), blk, 0, stream>>>(
      hb, wf2b,wf2b,wf2b, bf2,bf2,bf2, xb, accbuf,g1,be1, accbuf + 256,
      x2b,x2b,x2b, 512, 128, 1.f);

  // 6. BN2 apply -> fp32 out
  bn_final<<<dim3(256), blk, 0, stream>>>((const uint32*)x2b, accbuf + 256, g2, be2, out);
}